// Round 27
// baseline (846.575 us; speedup 1.0000x reference)
//
#include <hip/hip_runtime.h>
#include <hip/hip_fp16.h>

#define NN 50000
#define TT 12
#define EE 800000
#define IN_C 32
#define HID 64
#define OUT_C 32
#define BSZ 64                        // nodes per bucket
#define NB ((NN + BSZ - 1) / BSZ)     // 782 buckets
#define EPB 16384                     // edges per bsort block
#define ABLK ((EE + EPB - 1) / EPB)   // 49
#define GT 4                          // timesteps per gate block
#define XPAIRS ((size_t)TT * NN * 16) // half2 elements in x

typedef _Float16 half8_t __attribute__((ext_vector_type(8)));
typedef float f32x4_t __attribute__((ext_vector_type(4)));

// ---------------- precompute folded gate matrices ----------------
// Mz = Wz @ Lz_w[:64] (32x64), Bz = bz @ Lz_w[:64] + Lz_b (64); same for h.
__global__ __launch_bounds__(64) void prep_kernel(
    const float* __restrict__ Wz, const float* __restrict__ bz,
    const float* __restrict__ Lzw, const float* __restrict__ Lzb,
    const float* __restrict__ Wh, const float* __restrict__ bh,
    const float* __restrict__ Lhw, const float* __restrict__ Lhb,
    float* __restrict__ Mz, float* __restrict__ Bz,
    float* __restrict__ Mh, float* __restrict__ Bh) {
  const int j = threadIdx.x;
  const int i = blockIdx.x;
  const int h = blockIdx.y;
  const float* W  = h ? Wh  : Wz;
  const float* b  = h ? bh  : bz;
  const float* L  = h ? Lhw : Lzw;
  const float* Lb = h ? Lhb : Lzb;
  float* M = h ? Mh : Mz;
  float* B = h ? Bh : Bz;
  if (i < IN_C) {
    float v = 0.f;
    for (int k = 0; k < HID; ++k) v += W[i * HID + k] * L[k * HID + j];
    M[i * HID + j] = v;
  } else {
    float v = Lb[j];
    for (int k = 0; k < HID; ++k) v += b[k] * L[k * HID + j];
    B[j] = v;
  }
}

// pack M into MFMA B-operand fp16 layout: B16[(g*4+cc)*64 + lane][i] =
// M_g[k = 8*(lane>>4)+i][col = cc*16 + (lane&15)]
__global__ __launch_bounds__(64) void prep_b16_kernel(
    const float* __restrict__ Mz, const float* __restrict__ Mh,
    _Float16* __restrict__ B16) {
  int l = threadIdx.x;
  int cc = blockIdx.x;  // coltile 0..3
  int g = blockIdx.y;   // 0=z, 1=h
  const float* M = g ? Mh : Mz;
#pragma unroll
  for (int i = 0; i < 8; ++i) {
    int k = (l >> 4) * 8 + i;
    int col = cc * 16 + (l & 15);
    B16[(((size_t)g * 4 + cc) * 64 + l) * 8 + i] = (_Float16)M[k * HID + col];
  }
}

// x [T,N,32] fp32 -> fp16 pairs
__global__ __launch_bounds__(256) void xconv_kernel(const float* __restrict__ x,
                                                    __half2* __restrict__ xh) {
  size_t i = (size_t)blockIdx.x * 256 + threadIdx.x;
  if (i < XPAIRS) {
    float2 f = ((const float2*)x)[i];
    xh[i] = __floats2half2_rn(f.x, f.y);
  }
}

// bsort v2: R26's block-private bucket sort (VALIDATED) + R18-style perm
// write-out. SAFE here because this kernel has ZERO cross-block interaction
// (local scan, no global cursor) — every output byte is a pure function of
// the block's private input slice. The ordered write pass makes consecutive
// threads write consecutive addresses: each 64B line is produced by one
// wave in one instant -> write amp ~1.0 (R26's claim-scattered fills paid
// 3.4x because lines filled across the block lifetime while the aggregate
// live set exceeded per-XCD L2).
__global__ __launch_bounds__(256) void bsort_kernel(
    const int* __restrict__ ei, const float* __restrict__ ew,
    unsigned long long* __restrict__ bin2G, int* __restrict__ runoffG,
    int tbase) {
  __shared__ int hist[NB];
  __shared__ int rnk[NB];
  __shared__ int lbase[NB + 1];
  __shared__ unsigned short perm[EPB];
  int tl = blockIdx.y;
  const int* src = ei + (size_t)(tbase + tl) * 2 * EE;
  const int* dst = src + EE;
  const float* w = ew + (size_t)(tbase + tl) * EE;
  int t = threadIdx.x;
  for (int i = t; i < NB; i += 256) { hist[i] = 0; rnk[i] = 0; }
  __syncthreads();
  int e0 = blockIdx.x * EPB;
  int cnt = min(EPB, EE - e0);
  // 1) histogram
  for (int i = t; i < cnt; i += 256) atomicAdd(&hist[dst[e0 + i] >> 6], 1);
  __syncthreads();
  if (t == 0) {  // 2) local exclusive scan
    int run = 0;
    for (int b = 0; b < NB; ++b) { lbase[b] = run; run += hist[b]; }
    lbase[NB] = run;  // == cnt
  }
  __syncthreads();
  int* rof = runoffG + ((size_t)tl * ABLK + blockIdx.x) * (NB + 1);
  for (int b = t; b < NB + 1; b += 256) rof[b] = lbase[b];
  // 3) place permutation (u16 local edge index)
  for (int i = t; i < cnt; i += 256) {
    int b = dst[e0 + i] >> 6;
    int pos = lbase[b] + atomicAdd(&rnk[b], 1);
    perm[pos] = (unsigned short)i;
  }
  __syncthreads();
  // 4) ordered write-out: consecutive i -> consecutive addresses
  unsigned long long* reg = bin2G + ((size_t)tl * ABLK + blockIdx.x) * EPB;
  for (int i = t; i < cnt; i += 256) {
    int el = perm[i];
    int d = dst[e0 + el], s = src[e0 + el];   // L2-hot 192KB window re-reads
    unsigned short hw = __half_as_ushort(__float2half_rn(w[e0 + el]));
    reg[i] = (unsigned long long)((unsigned)s | ((unsigned)(d & 63) << 16)) |
             ((unsigned long long)hw << 32);
  }
}

// deg v2 (VALIDATED R26): per (bucket,t) stream the bucket's 49 block-runs
// from bin2 and LDS-float-atomic the per-node weight sums -> dinv.
__global__ __launch_bounds__(256) void deg_kernel(
    const int* __restrict__ runoffG, const unsigned long long* __restrict__ bin2G,
    float* __restrict__ dinvA) {
  __shared__ float wsum[BSZ];
  int tl = blockIdx.y, b = blockIdx.x;
  int t = threadIdx.x;
  if (t < BSZ) wsum[t] = 0.f;
  __syncthreads();
  const int* runoff = runoffG + (size_t)tl * ABLK * (NB + 1);
  int g = t >> 5;      // lane-group 0..7
  int lane = t & 31;
  for (int blk = g; blk < ABLK; blk += 8) {
    int r0 = runoff[blk * (NB + 1) + b];
    int r1 = runoff[blk * (NB + 1) + b + 1];
    const unsigned long long* reg = bin2G + ((size_t)tl * ABLK + blk) * EPB;
    for (int i = r0 + lane; i < r1; i += 32) {
      unsigned long long u = reg[i];
      int dl = (int)((u >> 16) & 63u);
      atomicAdd(&wsum[dl], __half2float(__ushort_as_half((unsigned short)(u >> 32))));
    }
  }
  __syncthreads();
  int n = b * BSZ + t;
  if (t < BSZ && n < NN) dinvA[(size_t)tl * NN + n] = rsqrtf(1.0f + wsum[t]);
}

// bscan v2 (VALIDATED R26): bucket totals from runoff diffs + 1024-wide scan.
__global__ __launch_bounds__(1024) void bscan_kernel(const int* __restrict__ runoffG,
                                                     int* __restrict__ bbaseA) {
  __shared__ int s[1024];
  int tl = blockIdx.x, t = threadIdx.x;
  const int* runoff = runoffG + (size_t)tl * ABLK * (NB + 1);
  int v = 0;
  if (t < NB) {
    for (int blk = 0; blk < ABLK; ++blk)
      v += runoff[blk * (NB + 1) + t + 1] - runoff[blk * (NB + 1) + t];
  }
  s[t] = v;
  __syncthreads();
  for (int o = 1; o < 1024; o <<= 1) {
    int u = (t >= o) ? s[t - o] : 0;
    __syncthreads();
    s[t] += u;
    __syncthreads();
  }
  if (t < NB) bbaseA[(size_t)tl * NB + t] = s[t] - v;  // exclusive
}

// sort v3 (VALIDATED R26): two-pass (LDS hist -> scan-64 -> noff -> place),
// source = bin2 block-runs. sbuf writes per-bucket contiguous.
__global__ __launch_bounds__(256) void sort_kernel(
    const int* __restrict__ runoffG, const unsigned long long* __restrict__ bin2G,
    const float* __restrict__ dinvA, const int* __restrict__ bbaseA,
    unsigned* __restrict__ sbufG, int* __restrict__ noffG) {
  __shared__ int hist[BSZ + 1];
  __shared__ int plc[BSZ];
  int tl = blockIdx.y, b = blockIdx.x;
  int t = threadIdx.x;
  if (t < BSZ + 1) hist[t] = 0;
  __syncthreads();
  const int* runoff = runoffG + (size_t)tl * ABLK * (NB + 1);
  int g = t >> 5;      // lane-group 0..7
  int lane = t & 31;
  for (int blk = g; blk < ABLK; blk += 8) {
    int r0 = runoff[blk * (NB + 1) + b];
    int r1 = runoff[blk * (NB + 1) + b + 1];
    const unsigned long long* reg = bin2G + ((size_t)tl * ABLK + blk) * EPB;
    for (int i = r0 + lane; i < r1; i += 32)
      atomicAdd(&hist[(int)((reg[i] >> 16) & 63u)], 1);
  }
  __syncthreads();
  int base = bbaseA[(size_t)tl * NB + b];
  int* noff = noffG + (size_t)tl * (NN + 1);
  if (t == 0) {
    int run = 0;
#pragma unroll
    for (int i = 0; i < BSZ; ++i) {
      int c = hist[i];
      hist[i] = run;
      plc[i] = run;
      run += c;
    }
    hist[BSZ] = run;
    if (b == NB - 1) noff[NN] = base + run;  // == EE
  }
  __syncthreads();
  {
    int n = b * BSZ + t;
    if (t < BSZ && n < NN) noff[n] = base + hist[t];
  }
  const float* dinv = dinvA + (size_t)tl * NN;
  unsigned* sbuf = sbufG + (size_t)tl * EE;
  for (int blk = g; blk < ABLK; blk += 8) {
    int r0 = runoff[blk * (NB + 1) + b];
    int r1 = runoff[blk * (NB + 1) + b + 1];
    const unsigned long long* reg = bin2G + ((size_t)tl * ABLK + blk) * EPB;
    for (int i = r0 + lane; i < r1; i += 32) {
      unsigned long long u = reg[i];
      int s = (int)(u & 0xFFFFu);
      int dl = (int)((u >> 16) & 63u);
      float nm = __half2float(__ushort_as_half((unsigned short)(u >> 32))) * dinv[s];
      int pos = base + atomicAdd(&plc[dl], 1);
      sbuf[pos] = (unsigned)s |
                  ((unsigned)__half_as_ushort(__float2half_rn(nm)) << 16);
    }
  }
}

// Pass B1: pure gather, NO LDS / NO barriers; t-major grid keeps xh_t
// L2-resident (proven R13/R21). lane = {node-half, 8 edge-groups, 4
// channel-octs}; per-edge uint4 row reads -> 16 row-loads in flight/wave.
__global__ __launch_bounds__(256) void gather_y_kernel(
    const float* __restrict__ x, const __half2* __restrict__ xh,
    const float* __restrict__ dinvA, const int* __restrict__ noffG,
    const unsigned* __restrict__ sbufG, __half2* __restrict__ yG, int tbase) {
  int t = threadIdx.x;
  int w = t >> 6;            // wave 0..3
  int lane = t & 63;
  int h2 = lane >> 5;        // node half 0/1
  int g = (lane >> 2) & 7;   // edge group 0..7
  int cq = lane & 3;         // channel oct 0..3 (8 fp16 ch = uint4)
  int tl = blockIdx.y;
  int n = blockIdx.x * 8 + w * 2 + h2;  // NN % 8 == 0, no tail

  const float* dinv = dinvA + (size_t)tl * NN;
  const int* noff = noffG + (size_t)tl * (NN + 1);
  const unsigned* sbuf = sbufG + (size_t)tl * EE;
  const __half2* xht = xh + (size_t)(tbase + tl) * NN * 16;
  const float* xt = x + (size_t)(tbase + tl) * NN * IN_C;

  int e0 = noff[n], e1 = noff[n + 1];
  float v0 = 0.f, v1 = 0.f, v2 = 0.f, v3 = 0.f;
  float v4 = 0.f, v5 = 0.f, v6 = 0.f, v7 = 0.f;
  for (int e = e0 + g; e < e1; e += 8) {
    unsigned u = sbuf[e];  // 8 lanes same addr: broadcast
    float nm = __half2float(__ushort_as_half((unsigned short)(u >> 16)));
    uint4 xr = ((const uint4*)(xht + (size_t)(u & 0xFFFFu) * 16))[cq];
    const __half2* hp = (const __half2*)&xr;
    float2 f0 = __half22float2(hp[0]);
    float2 f1 = __half22float2(hp[1]);
    float2 f2 = __half22float2(hp[2]);
    float2 f3 = __half22float2(hp[3]);
    v0 += nm * f0.x; v1 += nm * f0.y;
    v2 += nm * f1.x; v3 += nm * f1.y;
    v4 += nm * f2.x; v5 += nm * f2.y;
    v6 += nm * f3.x; v7 += nm * f3.y;
  }
  // reduce over the 8 edge groups (lane bits 2,3,4 — stays in node half/oct)
#pragma unroll
  for (int m = 4; m <= 16; m <<= 1) {
    v0 += __shfl_xor(v0, m); v1 += __shfl_xor(v1, m);
    v2 += __shfl_xor(v2, m); v3 += __shfl_xor(v3, m);
    v4 += __shfl_xor(v4, m); v5 += __shfl_xor(v5, m);
    v6 += __shfl_xor(v6, m); v7 += __shfl_xor(v7, m);
  }
  if (g == 0) {  // 4 lanes per node x 8 ch = all 32 channels
    float dv = dinv[n];
    const float4* xr4 = (const float4*)(xt + (size_t)n * IN_C);
    float4 xs0 = xr4[cq * 2];      // fp32 self-loop, ch cq*8 .. cq*8+3
    float4 xs1 = xr4[cq * 2 + 1];  // ch cq*8+4 .. cq*8+7
    __half2 o[4];
    o[0] = __floats2half2_rn(dv * (v0 + dv * xs0.x), dv * (v1 + dv * xs0.y));
    o[1] = __floats2half2_rn(dv * (v2 + dv * xs0.z), dv * (v3 + dv * xs0.w));
    o[2] = __floats2half2_rn(dv * (v4 + dv * xs1.x), dv * (v5 + dv * xs1.y));
    o[3] = __floats2half2_rn(dv * (v6 + dv * xs1.z), dv * (v7 + dv * xs1.w));
    __half2* yp = yG + ((size_t)tl * NN + n) * 16 + cq * 4;
    *(uint4*)yp = *(const uint4*)o;  // 16B store; 4 lanes fill the 64B row
  }
}

// Pass B2: MFMA gate (proven R17/R25/R26). P[64x64] = Y[64x32] @ M[32x64]
// per (64-node tile, t) via 16x16x32_f16; B-frags prepacked, loaded once.
__global__ __launch_bounds__(256) void gate_acc_kernel(
    const __half2* __restrict__ yG, const _Float16* __restrict__ B16,
    const float* __restrict__ Bz, const float* __restrict__ Bh,
    float* __restrict__ acc, int c) {
  int t = threadIdx.x;
  int w = t >> 6;
  int lane = t & 63;
  int nb = blockIdx.x * BSZ;
  int t0 = blockIdx.y * GT;
  int te = min(t0 + GT, c);

  half8_t bf[8];
#pragma unroll
  for (int q = 0; q < 8; ++q)
    bf[q] = *(const half8_t*)(B16 + ((size_t)q * 64 + lane) * 8);
  float bzv[4], bhv[4];
#pragma unroll
  for (int cc = 0; cc < 4; ++cc) {
    bzv[cc] = Bz[cc * 16 + (lane & 15)];
    bhv[cc] = Bh[cc * 16 + (lane & 15)];
  }
  float accr[16];
#pragma unroll
  for (int k = 0; k < 16; ++k) accr[k] = 0.f;

  const _Float16* yF = (const _Float16*)yG;
  int arow = nb + w * 16 + (lane & 15);   // A row this lane loads
  if (arow >= NN) arow = NN - 1;          // tail clamp (results discarded)
  int koff = (lane >> 4) * 8;             // k-offset within the row

  for (int tl = t0; tl < te; ++tl) {
    half8_t a = *(const half8_t*)(yF + ((size_t)tl * NN + arow) * 32 + koff);
    f32x4_t dz0 = {0.f, 0.f, 0.f, 0.f};
    f32x4_t dz[4], dh[4];
#pragma unroll
    for (int cc = 0; cc < 4; ++cc) {
      dz[cc] = __builtin_amdgcn_mfma_f32_16x16x32_f16(a, bf[cc], dz0, 0, 0, 0);
      dh[cc] = __builtin_amdgcn_mfma_f32_16x16x32_f16(a, bf[4 + cc], dz0, 0, 0, 0);
    }
#pragma unroll
    for (int cc = 0; cc < 4; ++cc) {
#pragma unroll
      for (int r = 0; r < 4; ++r) {
        float za = dz[cc][r] + bzv[cc];
        float ha = dh[cc][r] + bhv[cc];
        float z = 1.0f / (1.0f + __expf(-za));
        float th = 1.0f - 2.0f / (__expf(2.f * ha) + 1.0f);
        accr[cc * 4 + r] += (1.0f - z) * th;
      }
    }
  }
#pragma unroll
  for (int cc = 0; cc < 4; ++cc) {
#pragma unroll
    for (int r = 0; r < 4; ++r) {
      int n = nb + w * 16 + (lane >> 4) * 4 + r;
      int j = cc * 16 + (lane & 15);
      if (n < NN) atomicAdd(&acc[(size_t)n * HID + j], accr[cc * 4 + r]);
    }
  }
}

// out[n][o] = (acc[n]/T) . W_out[:,o] + b_out[o]
__global__ __launch_bounds__(256) void out_kernel(const float* __restrict__ acc,
                                                  const float* __restrict__ W_out,
                                                  const float* __restrict__ b_out,
                                                  float* __restrict__ out) {
  __shared__ float sW[HID * OUT_C], sB[OUT_C];
  for (int i = threadIdx.x; i < HID * OUT_C; i += 256) sW[i] = W_out[i];
  if (threadIdx.x < OUT_C) sB[threadIdx.x] = b_out[threadIdx.x];
  __syncthreads();
  unsigned tid = blockIdx.x * 256u + threadIdx.x;
  unsigned n = tid >> 5;
  int o = tid & 31;
  if (n >= NN) return;
  const float* ar = acc + (size_t)n * HID;
  float v = 0.f;
#pragma unroll
  for (int k = 0; k < HID; ++k) v += ar[k] * sW[k * OUT_C + o];
  out[(size_t)n * OUT_C + o] = v * (1.0f / (float)TT) + sB[o];
}

static inline char* alignp(char* p, size_t a) {
  return (char*)(((size_t)p + a - 1) & ~(a - 1));
}

extern "C" void kernel_launch(void* const* d_in, const int* in_sizes, int n_in,
                              void* d_out, int out_size, void* d_ws, size_t ws_size,
                              hipStream_t stream) {
  const float* x     = (const float*)d_in[0];  // [T,N,32]
  const int*   ei    = (const int*)d_in[1];    // [T,2,E]
  const float* ew    = (const float*)d_in[2];  // [T,E]
  const float* Wz    = (const float*)d_in[3];
  const float* bz    = (const float*)d_in[4];
  // d_in[5..6] (Wr,br) dead: H==0 so R unused
  const float* Wh    = (const float*)d_in[7];
  const float* bh    = (const float*)d_in[8];
  const float* Lz_w  = (const float*)d_in[9];
  const float* Lz_b  = (const float*)d_in[10];
  // d_in[11..12] (Lr) dead
  const float* Lh_w  = (const float*)d_in[13];
  const float* Lh_b  = (const float*)d_in[14];
  const float* W_out = (const float*)d_in[15];
  const float* b_out = (const float*)d_in[16];
  float* out = (float*)d_out;

  // per-t sizes (bytes)
  const size_t noffB  = (size_t)(NN + 1) * 4;
  const size_t dinvB  = (size_t)NN * 4;
  const size_t bbB    = (size_t)NB * 4;
  const size_t rofB   = (size_t)ABLK * (NB + 1) * 4;      // 153 KB
  const size_t sbufB  = (size_t)EE * 4;                   // 3.2 MB
  const size_t bin2B  = (size_t)ABLK * EPB * 8;           // 6.42 MB (y aliases)
  const size_t perT   = noffB + dinvB + bbB + rofB + sbufB + bin2B;  // ~10.2 MB
  const size_t xhB    = XPAIRS * 4;                       // 38.4 MB
  const size_t fixedB = 4 * ((size_t)2 * IN_C * HID + 2 * HID)
                      + 8192 + (size_t)NN * HID * 4 + xhB + 4096;  // ~51.3 MB

  int nt = 12;
  if (ws_size < fixedB + 12 * perT) {
    nt = (int)((ws_size - fixedB) / perT);
    if (nt < 1) nt = 1;
    if (nt > 12) nt = 12;
  }

  char* p = (char*)d_ws;
  unsigned long long* bin2 = (unsigned long long*)p;  // 8-aligned at base
  p += bin2B * nt;
  int* noffG  = (int*)p;          p += noffB * nt;
  float* dinv = (float*)p;        p += dinvB * nt;
  int* bbase  = (int*)p;          p += bbB * nt;
  int* runoff = (int*)p;          p += rofB * nt;
  unsigned* sbufG = (unsigned*)p; p += sbufB * nt;
  p = alignp(p, 16);
  _Float16* B16 = (_Float16*)p;   p += 8192;  // 4096 fp16 MFMA B-frags
  float* Mz = (float*)p;
  float* Mh = Mz + IN_C * HID;
  float* Bz = Mh + IN_C * HID;
  float* Bh = Bz + HID;
  float* acc = Bh + HID;  // [N,64]
  p = alignp((char*)(acc + (size_t)NN * HID), 256);
  __half2* xh = (__half2*)p;
  // y [nt,N,32] fp16 aliases the bin2 region: bin2 is dead after deg+sort;
  // stream order guarantees sort (reads bin2) < gather_y (writes y) <
  // gate_acc (reads y) < next chunk's bsort (rewrites bin2).
  __half2* yG = (__half2*)bin2;

  prep_kernel<<<dim3(IN_C + 1, 2), 64, 0, stream>>>(Wz, bz, Lz_w, Lz_b, Wh, bh,
                                                    Lh_w, Lh_b, Mz, Bz, Mh, Bh);
  prep_b16_kernel<<<dim3(4, 2), 64, 0, stream>>>(Mz, Mh, B16);
  xconv_kernel<<<(unsigned)((XPAIRS + 255) / 256), 256, 0, stream>>>(x, xh);
  hipMemsetAsync(acc, 0, (size_t)NN * HID * sizeof(float), stream);

  for (int tb = 0; tb < TT; tb += nt) {
    int c = (TT - tb < nt) ? (TT - tb) : nt;
    bsort_kernel<<<dim3(ABLK, c), 256, 0, stream>>>(ei, ew, bin2, runoff, tb);
    deg_kernel<<<dim3(NB, c), 256, 0, stream>>>(runoff, bin2, dinv);
    bscan_kernel<<<c, 1024, 0, stream>>>(runoff, bbase);
    sort_kernel<<<dim3(NB, c), 256, 0, stream>>>(runoff, bin2, dinv, bbase,
                                                 sbufG, noffG);
    gather_y_kernel<<<dim3(NN / 8, c), 256, 0, stream>>>(x, xh, dinv, noffG,
                                                         sbufG, yG, tb);
    gate_acc_kernel<<<dim3(NB, (c + GT - 1) / GT), 256, 0, stream>>>(
        yG, B16, Bz, Bh, acc, c);
  }

  out_kernel<<<(NN * OUT_C + 255) / 256, 256, 0, stream>>>(acc, W_out, b_out, out);
}

// Round 28
// 625.227 us; speedup vs baseline: 1.3540x; 1.3540x over previous
//
#include <hip/hip_runtime.h>
#include <hip/hip_fp16.h>

#define NN 50000
#define TT 12
#define EE 800000
#define IN_C 32
#define HID 64
#define OUT_C 32
#define BSZ 64                        // nodes per bucket
#define NB ((NN + BSZ - 1) / BSZ)     // 782 buckets
#define EPB 8192                      // edges per bsort block (ent fits LDS)
#define ABLK ((EE + EPB - 1) / EPB)   // 98
#define GT 4                          // timesteps per gate block
#define XPAIRS ((size_t)TT * NN * 16) // half2 elements in x

typedef _Float16 half8_t __attribute__((ext_vector_type(8)));
typedef float f32x4_t __attribute__((ext_vector_type(4)));

// ---------------- precompute folded gate matrices ----------------
// Mz = Wz @ Lz_w[:64] (32x64), Bz = bz @ Lz_w[:64] + Lz_b (64); same for h.
__global__ __launch_bounds__(64) void prep_kernel(
    const float* __restrict__ Wz, const float* __restrict__ bz,
    const float* __restrict__ Lzw, const float* __restrict__ Lzb,
    const float* __restrict__ Wh, const float* __restrict__ bh,
    const float* __restrict__ Lhw, const float* __restrict__ Lhb,
    float* __restrict__ Mz, float* __restrict__ Bz,
    float* __restrict__ Mh, float* __restrict__ Bh) {
  const int j = threadIdx.x;
  const int i = blockIdx.x;
  const int h = blockIdx.y;
  const float* W  = h ? Wh  : Wz;
  const float* b  = h ? bh  : bz;
  const float* L  = h ? Lhw : Lzw;
  const float* Lb = h ? Lhb : Lzb;
  float* M = h ? Mh : Mz;
  float* B = h ? Bh : Bz;
  if (i < IN_C) {
    float v = 0.f;
    for (int k = 0; k < HID; ++k) v += W[i * HID + k] * L[k * HID + j];
    M[i * HID + j] = v;
  } else {
    float v = Lb[j];
    for (int k = 0; k < HID; ++k) v += b[k] * L[k * HID + j];
    B[j] = v;
  }
}

// pack M into MFMA B-operand fp16 layout: B16[(g*4+cc)*64 + lane][i] =
// M_g[k = 8*(lane>>4)+i][col = cc*16 + (lane&15)]
__global__ __launch_bounds__(64) void prep_b16_kernel(
    const float* __restrict__ Mz, const float* __restrict__ Mh,
    _Float16* __restrict__ B16) {
  int l = threadIdx.x;
  int cc = blockIdx.x;  // coltile 0..3
  int g = blockIdx.y;   // 0=z, 1=h
  const float* M = g ? Mh : Mz;
#pragma unroll
  for (int i = 0; i < 8; ++i) {
    int k = (l >> 4) * 8 + i;
    int col = cc * 16 + (l & 15);
    B16[(((size_t)g * 4 + cc) * 64 + l) * 8 + i] = (_Float16)M[k * HID + col];
  }
}

// x [T,N,32] fp32 -> fp16 pairs
__global__ __launch_bounds__(256) void xconv_kernel(const float* __restrict__ x,
                                                    __half2* __restrict__ xh) {
  size_t i = (size_t)blockIdx.x * 256 + threadIdx.x;
  if (i < XPAIRS) {
    float2 f = ((const float2*)x)[i];
    xh[i] = __floats2half2_rn(f.x, f.y);
  }
}

// bsort v3: sort the block's 8192 edges INTO LDS (64 KB entry buffer), then
// stream out sequentially. R27's perm variant fixed WRITE (263->77 MB) but
// its permuted global re-reads cost 1.1 GB FETCH (random 4B probes, window
// set > per-XCD L2). Here all global reads are coalesced streams and all
// global writes are sequential: amp ~1.0 on both sides. Zero cross-block
// interaction (pure function of the block's input slice).
__global__ __launch_bounds__(256) void bsort_kernel(
    const int* __restrict__ ei, const float* __restrict__ ew,
    unsigned long long* __restrict__ bin2G, int* __restrict__ runoffG,
    int tbase) {
  __shared__ int hist[NB];
  __shared__ int rnk[NB];
  __shared__ int lbase[NB + 1];
  __shared__ unsigned long long sent[EPB];  // 64 KB sorted-entry buffer
  int tl = blockIdx.y;
  const int* src = ei + (size_t)(tbase + tl) * 2 * EE;
  const int* dst = src + EE;
  const float* w = ew + (size_t)(tbase + tl) * EE;
  int t = threadIdx.x;
  for (int i = t; i < NB; i += 256) { hist[i] = 0; rnk[i] = 0; }
  __syncthreads();
  int e0 = blockIdx.x * EPB;
  int cnt = min(EPB, EE - e0);
  // 1) histogram (coalesced dst stream)
  for (int i = t; i < cnt; i += 256) atomicAdd(&hist[dst[e0 + i] >> 6], 1);
  __syncthreads();
  if (t == 0) {  // 2) local exclusive scan
    int run = 0;
    for (int b = 0; b < NB; ++b) { lbase[b] = run; run += hist[b]; }
    lbase[NB] = run;  // == cnt
  }
  __syncthreads();
  int* rof = runoffG + ((size_t)tl * ABLK + blockIdx.x) * (NB + 1);
  for (int b = t; b < NB + 1; b += 256) rof[b] = lbase[b];
  // 3) place full entries into LDS at sorted positions (coalesced global
  //    reads; LDS scatter writes are cheap)
  for (int i = t; i < cnt; i += 256) {
    int d = dst[e0 + i], s = src[e0 + i];
    int b = d >> 6;
    unsigned short hw = __half_as_ushort(__float2half_rn(w[e0 + i]));
    int pos = lbase[b] + atomicAdd(&rnk[b], 1);
    sent[pos] = (unsigned long long)((unsigned)s | ((unsigned)(d & 63) << 16)) |
                ((unsigned long long)hw << 32);
  }
  __syncthreads();
  // 4) sequential write-out: linear LDS read -> sequential global write
  unsigned long long* reg = bin2G + ((size_t)tl * ABLK + blockIdx.x) * EPB;
  for (int i = t; i < cnt; i += 256) reg[i] = sent[i];
}

// deg v2 (VALIDATED R26): per (bucket,t) stream the bucket's block-runs
// from bin2 and LDS-float-atomic the per-node weight sums -> dinv.
__global__ __launch_bounds__(256) void deg_kernel(
    const int* __restrict__ runoffG, const unsigned long long* __restrict__ bin2G,
    float* __restrict__ dinvA) {
  __shared__ float wsum[BSZ];
  int tl = blockIdx.y, b = blockIdx.x;
  int t = threadIdx.x;
  if (t < BSZ) wsum[t] = 0.f;
  __syncthreads();
  const int* runoff = runoffG + (size_t)tl * ABLK * (NB + 1);
  int g = t >> 5;      // lane-group 0..7
  int lane = t & 31;
  for (int blk = g; blk < ABLK; blk += 8) {
    int r0 = runoff[blk * (NB + 1) + b];
    int r1 = runoff[blk * (NB + 1) + b + 1];
    const unsigned long long* reg = bin2G + ((size_t)tl * ABLK + blk) * EPB;
    for (int i = r0 + lane; i < r1; i += 32) {
      unsigned long long u = reg[i];
      int dl = (int)((u >> 16) & 63u);
      atomicAdd(&wsum[dl], __half2float(__ushort_as_half((unsigned short)(u >> 32))));
    }
  }
  __syncthreads();
  int n = b * BSZ + t;
  if (t < BSZ && n < NN) dinvA[(size_t)tl * NN + n] = rsqrtf(1.0f + wsum[t]);
}

// bscan v2 (VALIDATED R26): bucket totals from runoff diffs + 1024-wide scan.
__global__ __launch_bounds__(1024) void bscan_kernel(const int* __restrict__ runoffG,
                                                     int* __restrict__ bbaseA) {
  __shared__ int s[1024];
  int tl = blockIdx.x, t = threadIdx.x;
  const int* runoff = runoffG + (size_t)tl * ABLK * (NB + 1);
  int v = 0;
  if (t < NB) {
    for (int blk = 0; blk < ABLK; ++blk)
      v += runoff[blk * (NB + 1) + t + 1] - runoff[blk * (NB + 1) + t];
  }
  s[t] = v;
  __syncthreads();
  for (int o = 1; o < 1024; o <<= 1) {
    int u = (t >= o) ? s[t - o] : 0;
    __syncthreads();
    s[t] += u;
    __syncthreads();
  }
  if (t < NB) bbaseA[(size_t)tl * NB + t] = s[t] - v;  // exclusive
}

// sort v3 (VALIDATED R26): two-pass (LDS hist -> scan-64 -> noff -> place),
// source = bin2 block-runs. sbuf writes per-bucket contiguous.
__global__ __launch_bounds__(256) void sort_kernel(
    const int* __restrict__ runoffG, const unsigned long long* __restrict__ bin2G,
    const float* __restrict__ dinvA, const int* __restrict__ bbaseA,
    unsigned* __restrict__ sbufG, int* __restrict__ noffG) {
  __shared__ int hist[BSZ + 1];
  __shared__ int plc[BSZ];
  int tl = blockIdx.y, b = blockIdx.x;
  int t = threadIdx.x;
  if (t < BSZ + 1) hist[t] = 0;
  __syncthreads();
  const int* runoff = runoffG + (size_t)tl * ABLK * (NB + 1);
  int g = t >> 5;      // lane-group 0..7
  int lane = t & 31;
  for (int blk = g; blk < ABLK; blk += 8) {
    int r0 = runoff[blk * (NB + 1) + b];
    int r1 = runoff[blk * (NB + 1) + b + 1];
    const unsigned long long* reg = bin2G + ((size_t)tl * ABLK + blk) * EPB;
    for (int i = r0 + lane; i < r1; i += 32)
      atomicAdd(&hist[(int)((reg[i] >> 16) & 63u)], 1);
  }
  __syncthreads();
  int base = bbaseA[(size_t)tl * NB + b];
  int* noff = noffG + (size_t)tl * (NN + 1);
  if (t == 0) {
    int run = 0;
#pragma unroll
    for (int i = 0; i < BSZ; ++i) {
      int c = hist[i];
      hist[i] = run;
      plc[i] = run;
      run += c;
    }
    hist[BSZ] = run;
    if (b == NB - 1) noff[NN] = base + run;  // == EE
  }
  __syncthreads();
  {
    int n = b * BSZ + t;
    if (t < BSZ && n < NN) noff[n] = base + hist[t];
  }
  const float* dinv = dinvA + (size_t)tl * NN;
  unsigned* sbuf = sbufG + (size_t)tl * EE;
  for (int blk = g; blk < ABLK; blk += 8) {
    int r0 = runoff[blk * (NB + 1) + b];
    int r1 = runoff[blk * (NB + 1) + b + 1];
    const unsigned long long* reg = bin2G + ((size_t)tl * ABLK + blk) * EPB;
    for (int i = r0 + lane; i < r1; i += 32) {
      unsigned long long u = reg[i];
      int s = (int)(u & 0xFFFFu);
      int dl = (int)((u >> 16) & 63u);
      float nm = __half2float(__ushort_as_half((unsigned short)(u >> 32))) * dinv[s];
      int pos = base + atomicAdd(&plc[dl], 1);
      sbuf[pos] = (unsigned)s |
                  ((unsigned)__half_as_ushort(__float2half_rn(nm)) << 16);
    }
  }
}

// Pass B1: pure gather, NO LDS / NO barriers; t-major grid keeps xh_t
// L2-resident (proven R13/R21). lane = {node-half, 8 edge-groups, 4
// channel-octs}; per-edge uint4 row reads -> 16 row-loads in flight/wave.
__global__ __launch_bounds__(256) void gather_y_kernel(
    const float* __restrict__ x, const __half2* __restrict__ xh,
    const float* __restrict__ dinvA, const int* __restrict__ noffG,
    const unsigned* __restrict__ sbufG, __half2* __restrict__ yG, int tbase) {
  int t = threadIdx.x;
  int w = t >> 6;            // wave 0..3
  int lane = t & 63;
  int h2 = lane >> 5;        // node half 0/1
  int g = (lane >> 2) & 7;   // edge group 0..7
  int cq = lane & 3;         // channel oct 0..3 (8 fp16 ch = uint4)
  int tl = blockIdx.y;
  int n = blockIdx.x * 8 + w * 2 + h2;  // NN % 8 == 0, no tail

  const float* dinv = dinvA + (size_t)tl * NN;
  const int* noff = noffG + (size_t)tl * (NN + 1);
  const unsigned* sbuf = sbufG + (size_t)tl * EE;
  const __half2* xht = xh + (size_t)(tbase + tl) * NN * 16;
  const float* xt = x + (size_t)(tbase + tl) * NN * IN_C;

  int e0 = noff[n], e1 = noff[n + 1];
  float v0 = 0.f, v1 = 0.f, v2 = 0.f, v3 = 0.f;
  float v4 = 0.f, v5 = 0.f, v6 = 0.f, v7 = 0.f;
  for (int e = e0 + g; e < e1; e += 8) {
    unsigned u = sbuf[e];  // 8 lanes same addr: broadcast
    float nm = __half2float(__ushort_as_half((unsigned short)(u >> 16)));
    uint4 xr = ((const uint4*)(xht + (size_t)(u & 0xFFFFu) * 16))[cq];
    const __half2* hp = (const __half2*)&xr;
    float2 f0 = __half22float2(hp[0]);
    float2 f1 = __half22float2(hp[1]);
    float2 f2 = __half22float2(hp[2]);
    float2 f3 = __half22float2(hp[3]);
    v0 += nm * f0.x; v1 += nm * f0.y;
    v2 += nm * f1.x; v3 += nm * f1.y;
    v4 += nm * f2.x; v5 += nm * f2.y;
    v6 += nm * f3.x; v7 += nm * f3.y;
  }
  // reduce over the 8 edge groups (lane bits 2,3,4 — stays in node half/oct)
#pragma unroll
  for (int m = 4; m <= 16; m <<= 1) {
    v0 += __shfl_xor(v0, m); v1 += __shfl_xor(v1, m);
    v2 += __shfl_xor(v2, m); v3 += __shfl_xor(v3, m);
    v4 += __shfl_xor(v4, m); v5 += __shfl_xor(v5, m);
    v6 += __shfl_xor(v6, m); v7 += __shfl_xor(v7, m);
  }
  if (g == 0) {  // 4 lanes per node x 8 ch = all 32 channels
    float dv = dinv[n];
    const float4* xr4 = (const float4*)(xt + (size_t)n * IN_C);
    float4 xs0 = xr4[cq * 2];      // fp32 self-loop, ch cq*8 .. cq*8+3
    float4 xs1 = xr4[cq * 2 + 1];  // ch cq*8+4 .. cq*8+7
    __half2 o[4];
    o[0] = __floats2half2_rn(dv * (v0 + dv * xs0.x), dv * (v1 + dv * xs0.y));
    o[1] = __floats2half2_rn(dv * (v2 + dv * xs0.z), dv * (v3 + dv * xs0.w));
    o[2] = __floats2half2_rn(dv * (v4 + dv * xs1.x), dv * (v5 + dv * xs1.y));
    o[3] = __floats2half2_rn(dv * (v6 + dv * xs1.z), dv * (v7 + dv * xs1.w));
    __half2* yp = yG + ((size_t)tl * NN + n) * 16 + cq * 4;
    *(uint4*)yp = *(const uint4*)o;  // 16B store; 4 lanes fill the 64B row
  }
}

// Pass B2: MFMA gate (proven R17/R25/R26). P[64x64] = Y[64x32] @ M[32x64]
// per (64-node tile, t) via 16x16x32_f16; B-frags prepacked, loaded once.
__global__ __launch_bounds__(256) void gate_acc_kernel(
    const __half2* __restrict__ yG, const _Float16* __restrict__ B16,
    const float* __restrict__ Bz, const float* __restrict__ Bh,
    float* __restrict__ acc, int c) {
  int t = threadIdx.x;
  int w = t >> 6;
  int lane = t & 63;
  int nb = blockIdx.x * BSZ;
  int t0 = blockIdx.y * GT;
  int te = min(t0 + GT, c);

  half8_t bf[8];
#pragma unroll
  for (int q = 0; q < 8; ++q)
    bf[q] = *(const half8_t*)(B16 + ((size_t)q * 64 + lane) * 8);
  float bzv[4], bhv[4];
#pragma unroll
  for (int cc = 0; cc < 4; ++cc) {
    bzv[cc] = Bz[cc * 16 + (lane & 15)];
    bhv[cc] = Bh[cc * 16 + (lane & 15)];
  }
  float accr[16];
#pragma unroll
  for (int k = 0; k < 16; ++k) accr[k] = 0.f;

  const _Float16* yF = (const _Float16*)yG;
  int arow = nb + w * 16 + (lane & 15);   // A row this lane loads
  if (arow >= NN) arow = NN - 1;          // tail clamp (results discarded)
  int koff = (lane >> 4) * 8;             // k-offset within the row

  for (int tl = t0; tl < te; ++tl) {
    half8_t a = *(const half8_t*)(yF + ((size_t)tl * NN + arow) * 32 + koff);
    f32x4_t dz0 = {0.f, 0.f, 0.f, 0.f};
    f32x4_t dz[4], dh[4];
#pragma unroll
    for (int cc = 0; cc < 4; ++cc) {
      dz[cc] = __builtin_amdgcn_mfma_f32_16x16x32_f16(a, bf[cc], dz0, 0, 0, 0);
      dh[cc] = __builtin_amdgcn_mfma_f32_16x16x32_f16(a, bf[4 + cc], dz0, 0, 0, 0);
    }
#pragma unroll
    for (int cc = 0; cc < 4; ++cc) {
#pragma unroll
      for (int r = 0; r < 4; ++r) {
        float za = dz[cc][r] + bzv[cc];
        float ha = dh[cc][r] + bhv[cc];
        float z = 1.0f / (1.0f + __expf(-za));
        float th = 1.0f - 2.0f / (__expf(2.f * ha) + 1.0f);
        accr[cc * 4 + r] += (1.0f - z) * th;
      }
    }
  }
#pragma unroll
  for (int cc = 0; cc < 4; ++cc) {
#pragma unroll
    for (int r = 0; r < 4; ++r) {
      int n = nb + w * 16 + (lane >> 4) * 4 + r;
      int j = cc * 16 + (lane & 15);
      if (n < NN) atomicAdd(&acc[(size_t)n * HID + j], accr[cc * 4 + r]);
    }
  }
}

// out[n][o] = (acc[n]/T) . W_out[:,o] + b_out[o]
__global__ __launch_bounds__(256) void out_kernel(const float* __restrict__ acc,
                                                  const float* __restrict__ W_out,
                                                  const float* __restrict__ b_out,
                                                  float* __restrict__ out) {
  __shared__ float sW[HID * OUT_C], sB[OUT_C];
  for (int i = threadIdx.x; i < HID * OUT_C; i += 256) sW[i] = W_out[i];
  if (threadIdx.x < OUT_C) sB[threadIdx.x] = b_out[threadIdx.x];
  __syncthreads();
  unsigned tid = blockIdx.x * 256u + threadIdx.x;
  unsigned n = tid >> 5;
  int o = tid & 31;
  if (n >= NN) return;
  const float* ar = acc + (size_t)n * HID;
  float v = 0.f;
#pragma unroll
  for (int k = 0; k < HID; ++k) v += ar[k] * sW[k * OUT_C + o];
  out[(size_t)n * OUT_C + o] = v * (1.0f / (float)TT) + sB[o];
}

static inline char* alignp(char* p, size_t a) {
  return (char*)(((size_t)p + a - 1) & ~(a - 1));
}

extern "C" void kernel_launch(void* const* d_in, const int* in_sizes, int n_in,
                              void* d_out, int out_size, void* d_ws, size_t ws_size,
                              hipStream_t stream) {
  const float* x     = (const float*)d_in[0];  // [T,N,32]
  const int*   ei    = (const int*)d_in[1];    // [T,2,E]
  const float* ew    = (const float*)d_in[2];  // [T,E]
  const float* Wz    = (const float*)d_in[3];
  const float* bz    = (const float*)d_in[4];
  // d_in[5..6] (Wr,br) dead: H==0 so R unused
  const float* Wh    = (const float*)d_in[7];
  const float* bh    = (const float*)d_in[8];
  const float* Lz_w  = (const float*)d_in[9];
  const float* Lz_b  = (const float*)d_in[10];
  // d_in[11..12] (Lr) dead
  const float* Lh_w  = (const float*)d_in[13];
  const float* Lh_b  = (const float*)d_in[14];
  const float* W_out = (const float*)d_in[15];
  const float* b_out = (const float*)d_in[16];
  float* out = (float*)d_out;

  // per-t sizes (bytes)
  const size_t noffB  = (size_t)(NN + 1) * 4;
  const size_t dinvB  = (size_t)NN * 4;
  const size_t bbB    = (size_t)NB * 4;
  const size_t rofB   = (size_t)ABLK * (NB + 1) * 4;      // 307 KB
  const size_t sbufB  = (size_t)EE * 4;                   // 3.2 MB
  const size_t bin2B  = (size_t)ABLK * EPB * 8;           // 6.42 MB (y aliases)
  const size_t perT   = noffB + dinvB + bbB + rofB + sbufB + bin2B;  // ~10.4 MB
  const size_t xhB    = XPAIRS * 4;                       // 38.4 MB
  const size_t fixedB = 4 * ((size_t)2 * IN_C * HID + 2 * HID)
                      + 8192 + (size_t)NN * HID * 4 + xhB + 4096;  // ~51.3 MB

  int nt = 12;
  if (ws_size < fixedB + 12 * perT) {
    nt = (int)((ws_size - fixedB) / perT);
    if (nt < 1) nt = 1;
    if (nt > 12) nt = 12;
  }

  char* p = (char*)d_ws;
  unsigned long long* bin2 = (unsigned long long*)p;  // 8-aligned at base
  p += bin2B * nt;
  int* noffG  = (int*)p;          p += noffB * nt;
  float* dinv = (float*)p;        p += dinvB * nt;
  int* bbase  = (int*)p;          p += bbB * nt;
  int* runoff = (int*)p;          p += rofB * nt;
  unsigned* sbufG = (unsigned*)p; p += sbufB * nt;
  p = alignp(p, 16);
  _Float16* B16 = (_Float16*)p;   p += 8192;  // 4096 fp16 MFMA B-frags
  float* Mz = (float*)p;
  float* Mh = Mz + IN_C * HID;
  float* Bz = Mh + IN_C * HID;
  float* Bh = Bz + HID;
  float* acc = Bh + HID;  // [N,64]
  p = alignp((char*)(acc + (size_t)NN * HID), 256);
  __half2* xh = (__half2*)p;
  // y [nt,N,32] fp16 aliases the bin2 region: bin2 is dead after deg+sort;
  // stream order guarantees sort (reads bin2) < gather_y (writes y) <
  // gate_acc (reads y) < next chunk's bsort (rewrites bin2).
  __half2* yG = (__half2*)bin2;

  prep_kernel<<<dim3(IN_C + 1, 2), 64, 0, stream>>>(Wz, bz, Lz_w, Lz_b, Wh, bh,
                                                    Lh_w, Lh_b, Mz, Bz, Mh, Bh);
  prep_b16_kernel<<<dim3(4, 2), 64, 0, stream>>>(Mz, Mh, B16);
  xconv_kernel<<<(unsigned)((XPAIRS + 255) / 256), 256, 0, stream>>>(x, xh);
  hipMemsetAsync(acc, 0, (size_t)NN * HID * sizeof(float), stream);

  for (int tb = 0; tb < TT; tb += nt) {
    int c = (TT - tb < nt) ? (TT - tb) : nt;
    bsort_kernel<<<dim3(ABLK, c), 256, 0, stream>>>(ei, ew, bin2, runoff, tb);
    deg_kernel<<<dim3(NB, c), 256, 0, stream>>>(runoff, bin2, dinv);
    bscan_kernel<<<c, 1024, 0, stream>>>(runoff, bbase);
    sort_kernel<<<dim3(NB, c), 256, 0, stream>>>(runoff, bin2, dinv, bbase,
                                                 sbufG, noffG);
    gather_y_kernel<<<dim3(NN / 8, c), 256, 0, stream>>>(x, xh, dinv, noffG,
                                                         sbufG, yG, tb);
    gate_acc_kernel<<<dim3(NB, (c + GT - 1) / GT), 256, 0, stream>>>(
        yG, B16, Bz, Bh, acc, c);
  }

  out_kernel<<<(NN * OUT_C + 255) / 256, 256, 0, stream>>>(acc, W_out, b_out, out);
}

// Round 29
// 572.561 us; speedup vs baseline: 1.4786x; 1.0920x over previous
//
#include <hip/hip_runtime.h>
#include <hip/hip_fp16.h>

#define NN 50000
#define TT 12
#define EE 800000
#define IN_C 32
#define HID 64
#define OUT_C 32
#define BSZ 64                        // nodes per bucket
#define NB ((NN + BSZ - 1) / BSZ)     // 782 buckets
#define EPB 8192                      // edges per bsort block (ent fits LDS)
#define ABLK ((EE + EPB - 1) / EPB)   // 98
#define GT 4                          // timesteps per gate block
#define XPAIRS ((size_t)TT * NN * 16) // half2 elements in x

typedef _Float16 half8_t __attribute__((ext_vector_type(8)));
typedef float f32x4_t __attribute__((ext_vector_type(4)));

// ---------------- precompute folded gate matrices ----------------
// Mz = Wz @ Lz_w[:64] (32x64), Bz = bz @ Lz_w[:64] + Lz_b (64); same for h.
__global__ __launch_bounds__(64) void prep_kernel(
    const float* __restrict__ Wz, const float* __restrict__ bz,
    const float* __restrict__ Lzw, const float* __restrict__ Lzb,
    const float* __restrict__ Wh, const float* __restrict__ bh,
    const float* __restrict__ Lhw, const float* __restrict__ Lhb,
    float* __restrict__ Mz, float* __restrict__ Bz,
    float* __restrict__ Mh, float* __restrict__ Bh) {
  const int j = threadIdx.x;
  const int i = blockIdx.x;
  const int h = blockIdx.y;
  const float* W  = h ? Wh  : Wz;
  const float* b  = h ? bh  : bz;
  const float* L  = h ? Lhw : Lzw;
  const float* Lb = h ? Lhb : Lzb;
  float* M = h ? Mh : Mz;
  float* B = h ? Bh : Bz;
  if (i < IN_C) {
    float v = 0.f;
    for (int k = 0; k < HID; ++k) v += W[i * HID + k] * L[k * HID + j];
    M[i * HID + j] = v;
  } else {
    float v = Lb[j];
    for (int k = 0; k < HID; ++k) v += b[k] * L[k * HID + j];
    B[j] = v;
  }
}

// pack M into MFMA B-operand fp16 layout: B16[(g*4+cc)*64 + lane][i] =
// M_g[k = 8*(lane>>4)+i][col = cc*16 + (lane&15)]
__global__ __launch_bounds__(64) void prep_b16_kernel(
    const float* __restrict__ Mz, const float* __restrict__ Mh,
    _Float16* __restrict__ B16) {
  int l = threadIdx.x;
  int cc = blockIdx.x;  // coltile 0..3
  int g = blockIdx.y;   // 0=z, 1=h
  const float* M = g ? Mh : Mz;
#pragma unroll
  for (int i = 0; i < 8; ++i) {
    int k = (l >> 4) * 8 + i;
    int col = cc * 16 + (l & 15);
    B16[(((size_t)g * 4 + cc) * 64 + l) * 8 + i] = (_Float16)M[k * HID + col];
  }
}

// x [T,N,32] fp32 -> fp16 pairs
__global__ __launch_bounds__(256) void xconv_kernel(const float* __restrict__ x,
                                                    __half2* __restrict__ xh) {
  size_t i = (size_t)blockIdx.x * 256 + threadIdx.x;
  if (i < XPAIRS) {
    float2 f = ((const float2*)x)[i];
    xh[i] = __floats2half2_rn(f.x, f.y);
  }
}

// bsort v3 (VALIDATED R28): sort the block's 8192 edges INTO LDS (64 KB
// entry buffer), then stream out sequentially. Coalesced reads, sequential
// writes: amp ~1.0 both sides. Zero cross-block interaction.
__global__ __launch_bounds__(256) void bsort_kernel(
    const int* __restrict__ ei, const float* __restrict__ ew,
    unsigned long long* __restrict__ bin2G, int* __restrict__ runoffG,
    int tbase) {
  __shared__ int hist[NB];
  __shared__ int rnk[NB];
  __shared__ int lbase[NB + 1];
  __shared__ unsigned long long sent[EPB];  // 64 KB sorted-entry buffer
  int tl = blockIdx.y;
  const int* src = ei + (size_t)(tbase + tl) * 2 * EE;
  const int* dst = src + EE;
  const float* w = ew + (size_t)(tbase + tl) * EE;
  int t = threadIdx.x;
  for (int i = t; i < NB; i += 256) { hist[i] = 0; rnk[i] = 0; }
  __syncthreads();
  int e0 = blockIdx.x * EPB;
  int cnt = min(EPB, EE - e0);
  for (int i = t; i < cnt; i += 256) atomicAdd(&hist[dst[e0 + i] >> 6], 1);
  __syncthreads();
  if (t == 0) {
    int run = 0;
    for (int b = 0; b < NB; ++b) { lbase[b] = run; run += hist[b]; }
    lbase[NB] = run;  // == cnt
  }
  __syncthreads();
  int* rof = runoffG + ((size_t)tl * ABLK + blockIdx.x) * (NB + 1);
  for (int b = t; b < NB + 1; b += 256) rof[b] = lbase[b];
  for (int i = t; i < cnt; i += 256) {
    int d = dst[e0 + i], s = src[e0 + i];
    int b = d >> 6;
    unsigned short hw = __half_as_ushort(__float2half_rn(w[e0 + i]));
    int pos = lbase[b] + atomicAdd(&rnk[b], 1);
    sent[pos] = (unsigned long long)((unsigned)s | ((unsigned)(d & 63) << 16)) |
                ((unsigned long long)hw << 32);
  }
  __syncthreads();
  unsigned long long* reg = bin2G + ((size_t)tl * ABLK + blockIdx.x) * EPB;
  for (int i = t; i < cnt; i += 256) reg[i] = sent[i];
}

// deg v3: stream the bucket's block-runs from bin2; LDS-float-atomic wsum
// AND LDS-int-atomic per-node counts; thread-0 scan-64 -> loff (within-
// bucket exclusive offsets, exact integers). Saves sort's hist pass.
__global__ __launch_bounds__(256) void deg_kernel(
    const int* __restrict__ runoffG, const unsigned long long* __restrict__ bin2G,
    float* __restrict__ dinvA, int* __restrict__ loffA) {
  __shared__ float wsum[BSZ];
  __shared__ int cnt[BSZ];
  __shared__ int loff[BSZ];
  int tl = blockIdx.y, b = blockIdx.x;
  int t = threadIdx.x;
  if (t < BSZ) { wsum[t] = 0.f; cnt[t] = 0; }
  __syncthreads();
  const int* runoff = runoffG + (size_t)tl * ABLK * (NB + 1);
  int g = t >> 5;      // lane-group 0..7
  int lane = t & 31;
  for (int blk = g; blk < ABLK; blk += 8) {
    int r0 = runoff[blk * (NB + 1) + b];
    int r1 = runoff[blk * (NB + 1) + b + 1];
    const unsigned long long* reg = bin2G + ((size_t)tl * ABLK + blk) * EPB;
    for (int i = r0 + lane; i < r1; i += 32) {
      unsigned long long u = reg[i];
      int dl = (int)((u >> 16) & 63u);
      atomicAdd(&wsum[dl], __half2float(__ushort_as_half((unsigned short)(u >> 32))));
      atomicAdd(&cnt[dl], 1);
    }
  }
  __syncthreads();
  if (t == 0) {
    int run = 0;
#pragma unroll
    for (int i = 0; i < BSZ; ++i) { loff[i] = run; run += cnt[i]; }
  }
  __syncthreads();
  int n = b * BSZ + t;
  if (t < BSZ && n < NN) {
    dinvA[(size_t)tl * NN + n] = rsqrtf(1.0f + wsum[t]);
    loffA[(size_t)tl * NN + n] = loff[t];
  }
}

// bscan v2 (VALIDATED R26): bucket totals from runoff diffs + 1024-wide scan.
__global__ __launch_bounds__(1024) void bscan_kernel(const int* __restrict__ runoffG,
                                                     int* __restrict__ bbaseA) {
  __shared__ int s[1024];
  int tl = blockIdx.x, t = threadIdx.x;
  const int* runoff = runoffG + (size_t)tl * ABLK * (NB + 1);
  int v = 0;
  if (t < NB) {
    for (int blk = 0; blk < ABLK; ++blk)
      v += runoff[blk * (NB + 1) + t + 1] - runoff[blk * (NB + 1) + t];
  }
  s[t] = v;
  __syncthreads();
  for (int o = 1; o < 1024; o <<= 1) {
    int u = (t >= o) ? s[t - o] : 0;
    __syncthreads();
    s[t] += u;
    __syncthreads();
  }
  if (t < NB) bbaseA[(size_t)tl * NB + t] = s[t] - v;  // exclusive
}

// sort v4: hist pass DELETED — plc/noff seeded from bbase[b] + loff[n]
// (deg v3's exact counts). Single bin2 read (R28's sort read it twice).
__global__ __launch_bounds__(256) void sort_kernel(
    const int* __restrict__ runoffG, const unsigned long long* __restrict__ bin2G,
    const float* __restrict__ dinvA, const int* __restrict__ bbaseA,
    const int* __restrict__ loffA, unsigned* __restrict__ sbufG,
    int* __restrict__ noffG) {
  __shared__ int plc[BSZ];
  int tl = blockIdx.y, b = blockIdx.x;
  int t = threadIdx.x;
  int base = bbaseA[(size_t)tl * NB + b];
  int* noff = noffG + (size_t)tl * (NN + 1);
  if (t < BSZ) {
    int n = b * BSZ + t;
    int v = (n < NN) ? base + loffA[(size_t)tl * NN + n] : base;
    plc[t] = v;
    if (n < NN) noff[n] = v;
  }
  if (b == 0 && t == 0) noff[NN] = EE;
  __syncthreads();
  const int* runoff = runoffG + (size_t)tl * ABLK * (NB + 1);
  const float* dinv = dinvA + (size_t)tl * NN;
  unsigned* sbuf = sbufG + (size_t)tl * EE;
  int g = t >> 5;      // lane-group 0..7
  int lane = t & 31;
  for (int blk = g; blk < ABLK; blk += 8) {
    int r0 = runoff[blk * (NB + 1) + b];
    int r1 = runoff[blk * (NB + 1) + b + 1];
    const unsigned long long* reg = bin2G + ((size_t)tl * ABLK + blk) * EPB;
    for (int i = r0 + lane; i < r1; i += 32) {
      unsigned long long u = reg[i];
      int s = (int)(u & 0xFFFFu);
      int dl = (int)((u >> 16) & 63u);
      float nm = __half2float(__ushort_as_half((unsigned short)(u >> 32))) * dinv[s];
      int pos = atomicAdd(&plc[dl], 1);
      sbuf[pos] = (unsigned)s |
                  ((unsigned)__half_as_ushort(__float2half_rn(nm)) << 16);
    }
  }
}

// Pass B1: pure gather, NO LDS / NO barriers; t-major grid keeps xh_t
// L2-resident (proven R13/R21/R28). Self-loop now read from the fp16 xh row
// (L2-hot) instead of fp32 x — saves 77 MB of HBM fetch (R28 counter calc).
__global__ __launch_bounds__(256) void gather_y_kernel(
    const __half2* __restrict__ xh,
    const float* __restrict__ dinvA, const int* __restrict__ noffG,
    const unsigned* __restrict__ sbufG, __half2* __restrict__ yG, int tbase) {
  int t = threadIdx.x;
  int w = t >> 6;            // wave 0..3
  int lane = t & 63;
  int h2 = lane >> 5;        // node half 0/1
  int g = (lane >> 2) & 7;   // edge group 0..7
  int cq = lane & 3;         // channel oct 0..3 (8 fp16 ch = uint4)
  int tl = blockIdx.y;
  int n = blockIdx.x * 8 + w * 2 + h2;  // NN % 8 == 0, no tail

  const float* dinv = dinvA + (size_t)tl * NN;
  const int* noff = noffG + (size_t)tl * (NN + 1);
  const unsigned* sbuf = sbufG + (size_t)tl * EE;
  const __half2* xht = xh + (size_t)(tbase + tl) * NN * 16;

  int e0 = noff[n], e1 = noff[n + 1];
  float v0 = 0.f, v1 = 0.f, v2 = 0.f, v3 = 0.f;
  float v4 = 0.f, v5 = 0.f, v6 = 0.f, v7 = 0.f;
  for (int e = e0 + g; e < e1; e += 8) {
    unsigned u = sbuf[e];  // 8 lanes same addr: broadcast
    float nm = __half2float(__ushort_as_half((unsigned short)(u >> 16)));
    uint4 xr = ((const uint4*)(xht + (size_t)(u & 0xFFFFu) * 16))[cq];
    const __half2* hp = (const __half2*)&xr;
    float2 f0 = __half22float2(hp[0]);
    float2 f1 = __half22float2(hp[1]);
    float2 f2 = __half22float2(hp[2]);
    float2 f3 = __half22float2(hp[3]);
    v0 += nm * f0.x; v1 += nm * f0.y;
    v2 += nm * f1.x; v3 += nm * f1.y;
    v4 += nm * f2.x; v5 += nm * f2.y;
    v6 += nm * f3.x; v7 += nm * f3.y;
  }
  // reduce over the 8 edge groups (lane bits 2,3,4 — stays in node half/oct)
#pragma unroll
  for (int m = 4; m <= 16; m <<= 1) {
    v0 += __shfl_xor(v0, m); v1 += __shfl_xor(v1, m);
    v2 += __shfl_xor(v2, m); v3 += __shfl_xor(v3, m);
    v4 += __shfl_xor(v4, m); v5 += __shfl_xor(v5, m);
    v6 += __shfl_xor(v6, m); v7 += __shfl_xor(v7, m);
  }
  if (g == 0) {  // 4 lanes per node x 8 ch = all 32 channels
    float dv = dinv[n];
    uint4 xs = ((const uint4*)(xht + (size_t)n * 16))[cq];  // fp16 self-loop
    const __half2* hs = (const __half2*)&xs;
    float2 s0 = __half22float2(hs[0]);
    float2 s1 = __half22float2(hs[1]);
    float2 s2 = __half22float2(hs[2]);
    float2 s3 = __half22float2(hs[3]);
    __half2 o[4];
    o[0] = __floats2half2_rn(dv * (v0 + dv * s0.x), dv * (v1 + dv * s0.y));
    o[1] = __floats2half2_rn(dv * (v2 + dv * s1.x), dv * (v3 + dv * s1.y));
    o[2] = __floats2half2_rn(dv * (v4 + dv * s2.x), dv * (v5 + dv * s2.y));
    o[3] = __floats2half2_rn(dv * (v6 + dv * s3.x), dv * (v7 + dv * s3.y));
    __half2* yp = yG + ((size_t)tl * NN + n) * 16 + cq * 4;
    *(uint4*)yp = *(const uint4*)o;  // 16B store; 4 lanes fill the 64B row
  }
}

// Pass B2: MFMA gate (proven R17/R25/R26/R28). P[64x64] = Y[64x32] @
// M[32x64] per (64-node tile, t) via 16x16x32_f16; B-frags prepacked.
__global__ __launch_bounds__(256) void gate_acc_kernel(
    const __half2* __restrict__ yG, const _Float16* __restrict__ B16,
    const float* __restrict__ Bz, const float* __restrict__ Bh,
    float* __restrict__ acc, int c) {
  int t = threadIdx.x;
  int w = t >> 6;
  int lane = t & 63;
  int nb = blockIdx.x * BSZ;
  int t0 = blockIdx.y * GT;
  int te = min(t0 + GT, c);

  half8_t bf[8];
#pragma unroll
  for (int q = 0; q < 8; ++q)
    bf[q] = *(const half8_t*)(B16 + ((size_t)q * 64 + lane) * 8);
  float bzv[4], bhv[4];
#pragma unroll
  for (int cc = 0; cc < 4; ++cc) {
    bzv[cc] = Bz[cc * 16 + (lane & 15)];
    bhv[cc] = Bh[cc * 16 + (lane & 15)];
  }
  float accr[16];
#pragma unroll
  for (int k = 0; k < 16; ++k) accr[k] = 0.f;

  const _Float16* yF = (const _Float16*)yG;
  int arow = nb + w * 16 + (lane & 15);   // A row this lane loads
  if (arow >= NN) arow = NN - 1;          // tail clamp (results discarded)
  int koff = (lane >> 4) * 8;             // k-offset within the row

  for (int tl = t0; tl < te; ++tl) {
    half8_t a = *(const half8_t*)(yF + ((size_t)tl * NN + arow) * 32 + koff);
    f32x4_t dz0 = {0.f, 0.f, 0.f, 0.f};
    f32x4_t dz[4], dh[4];
#pragma unroll
    for (int cc = 0; cc < 4; ++cc) {
      dz[cc] = __builtin_amdgcn_mfma_f32_16x16x32_f16(a, bf[cc], dz0, 0, 0, 0);
      dh[cc] = __builtin_amdgcn_mfma_f32_16x16x32_f16(a, bf[4 + cc], dz0, 0, 0, 0);
    }
#pragma unroll
    for (int cc = 0; cc < 4; ++cc) {
#pragma unroll
      for (int r = 0; r < 4; ++r) {
        float za = dz[cc][r] + bzv[cc];
        float ha = dh[cc][r] + bhv[cc];
        float z = 1.0f / (1.0f + __expf(-za));
        float th = 1.0f - 2.0f / (__expf(2.f * ha) + 1.0f);
        accr[cc * 4 + r] += (1.0f - z) * th;
      }
    }
  }
#pragma unroll
  for (int cc = 0; cc < 4; ++cc) {
#pragma unroll
    for (int r = 0; r < 4; ++r) {
      int n = nb + w * 16 + (lane >> 4) * 4 + r;
      int j = cc * 16 + (lane & 15);
      if (n < NN) atomicAdd(&acc[(size_t)n * HID + j], accr[cc * 4 + r]);
    }
  }
}

// out[n][o] = (acc[n]/T) . W_out[:,o] + b_out[o]
__global__ __launch_bounds__(256) void out_kernel(const float* __restrict__ acc,
                                                  const float* __restrict__ W_out,
                                                  const float* __restrict__ b_out,
                                                  float* __restrict__ out) {
  __shared__ float sW[HID * OUT_C], sB[OUT_C];
  for (int i = threadIdx.x; i < HID * OUT_C; i += 256) sW[i] = W_out[i];
  if (threadIdx.x < OUT_C) sB[threadIdx.x] = b_out[threadIdx.x];
  __syncthreads();
  unsigned tid = blockIdx.x * 256u + threadIdx.x;
  unsigned n = tid >> 5;
  int o = tid & 31;
  if (n >= NN) return;
  const float* ar = acc + (size_t)n * HID;
  float v = 0.f;
#pragma unroll
  for (int k = 0; k < HID; ++k) v += ar[k] * sW[k * OUT_C + o];
  out[(size_t)n * OUT_C + o] = v * (1.0f / (float)TT) + sB[o];
}

static inline char* alignp(char* p, size_t a) {
  return (char*)(((size_t)p + a - 1) & ~(a - 1));
}

extern "C" void kernel_launch(void* const* d_in, const int* in_sizes, int n_in,
                              void* d_out, int out_size, void* d_ws, size_t ws_size,
                              hipStream_t stream) {
  const float* x     = (const float*)d_in[0];  // [T,N,32]
  const int*   ei    = (const int*)d_in[1];    // [T,2,E]
  const float* ew    = (const float*)d_in[2];  // [T,E]
  const float* Wz    = (const float*)d_in[3];
  const float* bz    = (const float*)d_in[4];
  // d_in[5..6] (Wr,br) dead: H==0 so R unused
  const float* Wh    = (const float*)d_in[7];
  const float* bh    = (const float*)d_in[8];
  const float* Lz_w  = (const float*)d_in[9];
  const float* Lz_b  = (const float*)d_in[10];
  // d_in[11..12] (Lr) dead
  const float* Lh_w  = (const float*)d_in[13];
  const float* Lh_b  = (const float*)d_in[14];
  const float* W_out = (const float*)d_in[15];
  const float* b_out = (const float*)d_in[16];
  float* out = (float*)d_out;

  // per-t sizes (bytes)
  const size_t noffB  = (size_t)(NN + 1) * 4;
  const size_t dinvB  = (size_t)NN * 4;
  const size_t loffB  = (size_t)NN * 4;
  const size_t bbB    = (size_t)NB * 4;
  const size_t rofB   = (size_t)ABLK * (NB + 1) * 4;      // 307 KB
  const size_t sbufB  = (size_t)EE * 4;                   // 3.2 MB
  const size_t bin2B  = (size_t)ABLK * EPB * 8;           // 6.42 MB (y aliases)
  const size_t perT   = noffB + dinvB + loffB + bbB + rofB + sbufB + bin2B;
  const size_t xhB    = XPAIRS * 4;                       // 38.4 MB
  const size_t fixedB = 4 * ((size_t)2 * IN_C * HID + 2 * HID)
                      + 8192 + (size_t)NN * HID * 4 + xhB + 4096;  // ~51.3 MB

  int nt = 12;
  if (ws_size < fixedB + 12 * perT) {
    nt = (int)((ws_size - fixedB) / perT);
    if (nt < 1) nt = 1;
    if (nt > 12) nt = 12;
  }

  char* p = (char*)d_ws;
  unsigned long long* bin2 = (unsigned long long*)p;  // 8-aligned at base
  p += bin2B * nt;
  int* noffG  = (int*)p;          p += noffB * nt;
  float* dinv = (float*)p;        p += dinvB * nt;
  int* loffG  = (int*)p;          p += loffB * nt;
  int* bbase  = (int*)p;          p += bbB * nt;
  int* runoff = (int*)p;          p += rofB * nt;
  unsigned* sbufG = (unsigned*)p; p += sbufB * nt;
  p = alignp(p, 16);
  _Float16* B16 = (_Float16*)p;   p += 8192;  // 4096 fp16 MFMA B-frags
  float* Mz = (float*)p;
  float* Mh = Mz + IN_C * HID;
  float* Bz = Mh + IN_C * HID;
  float* Bh = Bz + HID;
  float* acc = Bh + HID;  // [N,64]
  p = alignp((char*)(acc + (size_t)NN * HID), 256);
  __half2* xh = (__half2*)p;
  // y [nt,N,32] fp16 aliases the bin2 region: bin2 is dead after deg+sort;
  // stream order guarantees sort (reads bin2) < gather_y (writes y) <
  // gate_acc (reads y) < next chunk's bsort (rewrites bin2).
  __half2* yG = (__half2*)bin2;

  prep_kernel<<<dim3(IN_C + 1, 2), 64, 0, stream>>>(Wz, bz, Lz_w, Lz_b, Wh, bh,
                                                    Lh_w, Lh_b, Mz, Bz, Mh, Bh);
  prep_b16_kernel<<<dim3(4, 2), 64, 0, stream>>>(Mz, Mh, B16);
  xconv_kernel<<<(unsigned)((XPAIRS + 255) / 256), 256, 0, stream>>>(x, xh);
  hipMemsetAsync(acc, 0, (size_t)NN * HID * sizeof(float), stream);

  for (int tb = 0; tb < TT; tb += nt) {
    int c = (TT - tb < nt) ? (TT - tb) : nt;
    bsort_kernel<<<dim3(ABLK, c), 256, 0, stream>>>(ei, ew, bin2, runoff, tb);
    deg_kernel<<<dim3(NB, c), 256, 0, stream>>>(runoff, bin2, dinv, loffG);
    bscan_kernel<<<c, 1024, 0, stream>>>(runoff, bbase);
    sort_kernel<<<dim3(NB, c), 256, 0, stream>>>(runoff, bin2, dinv, bbase,
                                                 loffG, sbufG, noffG);
    gather_y_kernel<<<dim3(NN / 8, c), 256, 0, stream>>>(xh, dinv, noffG,
                                                         sbufG, yG, tb);
    gate_acc_kernel<<<dim3(NB, (c + GT - 1) / GT), 256, 0, stream>>>(
        yG, B16, Bz, Bh, acc, c);
  }

  out_kernel<<<(NN * OUT_C + 255) / 256, 256, 0, stream>>>(acc, W_out, b_out, out);
}

// Round 30
// 533.403 us; speedup vs baseline: 1.5871x; 1.0734x over previous
//
#include <hip/hip_runtime.h>
#include <hip/hip_fp16.h>

#define NN 50000
#define TT 12
#define EE 800000
#define IN_C 32
#define HID 64
#define OUT_C 32
#define BSZ 64                        // nodes per bucket
#define NB ((NN + BSZ - 1) / BSZ)     // 782 buckets
#define EPB 8192                      // edges per bsort block (ent fits LDS)
#define ABLK ((EE + EPB - 1) / EPB)   // 98
#define BST 512                       // bsort threads (8 waves: occupancy)
#define GT 4                          // timesteps per gate block
#define XPAIRS ((size_t)TT * NN * 16) // half2 elements in x

typedef _Float16 half8_t __attribute__((ext_vector_type(8)));
typedef float f32x4_t __attribute__((ext_vector_type(4)));

// ---------------- precompute folded gate matrices ----------------
// Mz = Wz @ Lz_w[:64] (32x64), Bz = bz @ Lz_w[:64] + Lz_b (64); same for h.
__global__ __launch_bounds__(64) void prep_kernel(
    const float* __restrict__ Wz, const float* __restrict__ bz,
    const float* __restrict__ Lzw, const float* __restrict__ Lzb,
    const float* __restrict__ Wh, const float* __restrict__ bh,
    const float* __restrict__ Lhw, const float* __restrict__ Lhb,
    float* __restrict__ Mz, float* __restrict__ Bz,
    float* __restrict__ Mh, float* __restrict__ Bh) {
  const int j = threadIdx.x;
  const int i = blockIdx.x;
  const int h = blockIdx.y;
  const float* W  = h ? Wh  : Wz;
  const float* b  = h ? bh  : bz;
  const float* L  = h ? Lhw : Lzw;
  const float* Lb = h ? Lhb : Lzb;
  float* M = h ? Mh : Mz;
  float* B = h ? Bh : Bz;
  if (i < IN_C) {
    float v = 0.f;
    for (int k = 0; k < HID; ++k) v += W[i * HID + k] * L[k * HID + j];
    M[i * HID + j] = v;
  } else {
    float v = Lb[j];
    for (int k = 0; k < HID; ++k) v += b[k] * L[k * HID + j];
    B[j] = v;
  }
}

// pack M into MFMA B-operand fp16 layout: B16[(g*4+cc)*64 + lane][i] =
// M_g[k = 8*(lane>>4)+i][col = cc*16 + (lane&15)]
__global__ __launch_bounds__(64) void prep_b16_kernel(
    const float* __restrict__ Mz, const float* __restrict__ Mh,
    _Float16* __restrict__ B16) {
  int l = threadIdx.x;
  int cc = blockIdx.x;  // coltile 0..3
  int g = blockIdx.y;   // 0=z, 1=h
  const float* M = g ? Mh : Mz;
#pragma unroll
  for (int i = 0; i < 8; ++i) {
    int k = (l >> 4) * 8 + i;
    int col = cc * 16 + (l & 15);
    B16[(((size_t)g * 4 + cc) * 64 + l) * 8 + i] = (_Float16)M[k * HID + col];
  }
}

// x [T,N,32] fp32 -> fp16 pairs
__global__ __launch_bounds__(256) void xconv_kernel(const float* __restrict__ x,
                                                    __half2* __restrict__ xh) {
  size_t i = (size_t)blockIdx.x * 256 + threadIdx.x;
  if (i < XPAIRS) {
    float2 f = ((const float2*)x)[i];
    xh[i] = __floats2half2_rn(f.x, f.y);
  }
}

// bsort v4: R28's validated LDS-staged sort + sequential streamout, now at
// 512 threads. R29 counters: 156us at 0.92 TB/s, Occ 17%, VALU 5.6% —
// latency-bound because 73.5 KB LDS caps 2 blocks/CU and 4 waves/block gave
// only 8 waves/CU. 8 waves/block doubles resident waves (16/CU) at the same
// LDS footprint. Layout/semantics identical.
__global__ __launch_bounds__(BST) void bsort_kernel(
    const int* __restrict__ ei, const float* __restrict__ ew,
    unsigned long long* __restrict__ bin2G, int* __restrict__ runoffG,
    int tbase) {
  __shared__ int hist[NB];
  __shared__ int rnk[NB];
  __shared__ int lbase[NB + 1];
  __shared__ unsigned long long sent[EPB];  // 64 KB sorted-entry buffer
  int tl = blockIdx.y;
  const int* src = ei + (size_t)(tbase + tl) * 2 * EE;
  const int* dst = src + EE;
  const float* w = ew + (size_t)(tbase + tl) * EE;
  int t = threadIdx.x;
  for (int i = t; i < NB; i += BST) { hist[i] = 0; rnk[i] = 0; }
  __syncthreads();
  int e0 = blockIdx.x * EPB;
  int cnt = min(EPB, EE - e0);
  for (int i = t; i < cnt; i += BST) atomicAdd(&hist[dst[e0 + i] >> 6], 1);
  __syncthreads();
  if (t == 0) {
    int run = 0;
    for (int b = 0; b < NB; ++b) { lbase[b] = run; run += hist[b]; }
    lbase[NB] = run;  // == cnt
  }
  __syncthreads();
  int* rof = runoffG + ((size_t)tl * ABLK + blockIdx.x) * (NB + 1);
  for (int b = t; b < NB + 1; b += BST) rof[b] = lbase[b];
  for (int i = t; i < cnt; i += BST) {
    int d = dst[e0 + i], s = src[e0 + i];
    int b = d >> 6;
    unsigned short hw = __half_as_ushort(__float2half_rn(w[e0 + i]));
    int pos = lbase[b] + atomicAdd(&rnk[b], 1);
    sent[pos] = (unsigned long long)((unsigned)s | ((unsigned)(d & 63) << 16)) |
                ((unsigned long long)hw << 32);
  }
  __syncthreads();
  unsigned long long* reg = bin2G + ((size_t)tl * ABLK + blockIdx.x) * EPB;
  for (int i = t; i < cnt; i += BST) reg[i] = sent[i];
}

// deg v3 (VALIDATED R29): stream the bucket's block-runs from bin2;
// LDS-float-atomic wsum AND LDS-int counts; thread-0 scan-64 -> loff.
__global__ __launch_bounds__(256) void deg_kernel(
    const int* __restrict__ runoffG, const unsigned long long* __restrict__ bin2G,
    float* __restrict__ dinvA, int* __restrict__ loffA) {
  __shared__ float wsum[BSZ];
  __shared__ int cnt[BSZ];
  __shared__ int loff[BSZ];
  int tl = blockIdx.y, b = blockIdx.x;
  int t = threadIdx.x;
  if (t < BSZ) { wsum[t] = 0.f; cnt[t] = 0; }
  __syncthreads();
  const int* runoff = runoffG + (size_t)tl * ABLK * (NB + 1);
  int g = t >> 5;      // lane-group 0..7
  int lane = t & 31;
  for (int blk = g; blk < ABLK; blk += 8) {
    int r0 = runoff[blk * (NB + 1) + b];
    int r1 = runoff[blk * (NB + 1) + b + 1];
    const unsigned long long* reg = bin2G + ((size_t)tl * ABLK + blk) * EPB;
    for (int i = r0 + lane; i < r1; i += 32) {
      unsigned long long u = reg[i];
      int dl = (int)((u >> 16) & 63u);
      atomicAdd(&wsum[dl], __half2float(__ushort_as_half((unsigned short)(u >> 32))));
      atomicAdd(&cnt[dl], 1);
    }
  }
  __syncthreads();
  if (t == 0) {
    int run = 0;
#pragma unroll
    for (int i = 0; i < BSZ; ++i) { loff[i] = run; run += cnt[i]; }
  }
  __syncthreads();
  int n = b * BSZ + t;
  if (t < BSZ && n < NN) {
    dinvA[(size_t)tl * NN + n] = rsqrtf(1.0f + wsum[t]);
    loffA[(size_t)tl * NN + n] = loff[t];
  }
}

// bscan v2 (VALIDATED R26): bucket totals from runoff diffs + 1024-wide scan.
__global__ __launch_bounds__(1024) void bscan_kernel(const int* __restrict__ runoffG,
                                                     int* __restrict__ bbaseA) {
  __shared__ int s[1024];
  int tl = blockIdx.x, t = threadIdx.x;
  const int* runoff = runoffG + (size_t)tl * ABLK * (NB + 1);
  int v = 0;
  if (t < NB) {
    for (int blk = 0; blk < ABLK; ++blk)
      v += runoff[blk * (NB + 1) + t + 1] - runoff[blk * (NB + 1) + t];
  }
  s[t] = v;
  __syncthreads();
  for (int o = 1; o < 1024; o <<= 1) {
    int u = (t >= o) ? s[t - o] : 0;
    __syncthreads();
    s[t] += u;
    __syncthreads();
  }
  if (t < NB) bbaseA[(size_t)tl * NB + t] = s[t] - v;  // exclusive
}

// sort v4 (VALIDATED R29): plc/noff seeded from bbase[b] + loff[n];
// single bin2 read; per-bucket contiguous sbuf writes.
__global__ __launch_bounds__(256) void sort_kernel(
    const int* __restrict__ runoffG, const unsigned long long* __restrict__ bin2G,
    const float* __restrict__ dinvA, const int* __restrict__ bbaseA,
    const int* __restrict__ loffA, unsigned* __restrict__ sbufG,
    int* __restrict__ noffG) {
  __shared__ int plc[BSZ];
  int tl = blockIdx.y, b = blockIdx.x;
  int t = threadIdx.x;
  int base = bbaseA[(size_t)tl * NB + b];
  int* noff = noffG + (size_t)tl * (NN + 1);
  if (t < BSZ) {
    int n = b * BSZ + t;
    int v = (n < NN) ? base + loffA[(size_t)tl * NN + n] : base;
    plc[t] = v;
    if (n < NN) noff[n] = v;
  }
  if (b == 0 && t == 0) noff[NN] = EE;
  __syncthreads();
  const int* runoff = runoffG + (size_t)tl * ABLK * (NB + 1);
  const float* dinv = dinvA + (size_t)tl * NN;
  unsigned* sbuf = sbufG + (size_t)tl * EE;
  int g = t >> 5;      // lane-group 0..7
  int lane = t & 31;
  for (int blk = g; blk < ABLK; blk += 8) {
    int r0 = runoff[blk * (NB + 1) + b];
    int r1 = runoff[blk * (NB + 1) + b + 1];
    const unsigned long long* reg = bin2G + ((size_t)tl * ABLK + blk) * EPB;
    for (int i = r0 + lane; i < r1; i += 32) {
      unsigned long long u = reg[i];
      int s = (int)(u & 0xFFFFu);
      int dl = (int)((u >> 16) & 63u);
      float nm = __half2float(__ushort_as_half((unsigned short)(u >> 32))) * dinv[s];
      int pos = atomicAdd(&plc[dl], 1);
      sbuf[pos] = (unsigned)s |
                  ((unsigned)__half_as_ushort(__float2half_rn(nm)) << 16);
    }
  }
}

// Pass B1 (VALIDATED R29): pure gather, NO LDS / NO barriers; t-major grid
// keeps xh_t L2-resident; fp16 self-loop from xh.
__global__ __launch_bounds__(256) void gather_y_kernel(
    const __half2* __restrict__ xh,
    const float* __restrict__ dinvA, const int* __restrict__ noffG,
    const unsigned* __restrict__ sbufG, __half2* __restrict__ yG, int tbase) {
  int t = threadIdx.x;
  int w = t >> 6;            // wave 0..3
  int lane = t & 63;
  int h2 = lane >> 5;        // node half 0/1
  int g = (lane >> 2) & 7;   // edge group 0..7
  int cq = lane & 3;         // channel oct 0..3 (8 fp16 ch = uint4)
  int tl = blockIdx.y;
  int n = blockIdx.x * 8 + w * 2 + h2;  // NN % 8 == 0, no tail

  const float* dinv = dinvA + (size_t)tl * NN;
  const int* noff = noffG + (size_t)tl * (NN + 1);
  const unsigned* sbuf = sbufG + (size_t)tl * EE;
  const __half2* xht = xh + (size_t)(tbase + tl) * NN * 16;

  int e0 = noff[n], e1 = noff[n + 1];
  float v0 = 0.f, v1 = 0.f, v2 = 0.f, v3 = 0.f;
  float v4 = 0.f, v5 = 0.f, v6 = 0.f, v7 = 0.f;
  for (int e = e0 + g; e < e1; e += 8) {
    unsigned u = sbuf[e];  // 8 lanes same addr: broadcast
    float nm = __half2float(__ushort_as_half((unsigned short)(u >> 16)));
    uint4 xr = ((const uint4*)(xht + (size_t)(u & 0xFFFFu) * 16))[cq];
    const __half2* hp = (const __half2*)&xr;
    float2 f0 = __half22float2(hp[0]);
    float2 f1 = __half22float2(hp[1]);
    float2 f2 = __half22float2(hp[2]);
    float2 f3 = __half22float2(hp[3]);
    v0 += nm * f0.x; v1 += nm * f0.y;
    v2 += nm * f1.x; v3 += nm * f1.y;
    v4 += nm * f2.x; v5 += nm * f2.y;
    v6 += nm * f3.x; v7 += nm * f3.y;
  }
  // reduce over the 8 edge groups (lane bits 2,3,4 — stays in node half/oct)
#pragma unroll
  for (int m = 4; m <= 16; m <<= 1) {
    v0 += __shfl_xor(v0, m); v1 += __shfl_xor(v1, m);
    v2 += __shfl_xor(v2, m); v3 += __shfl_xor(v3, m);
    v4 += __shfl_xor(v4, m); v5 += __shfl_xor(v5, m);
    v6 += __shfl_xor(v6, m); v7 += __shfl_xor(v7, m);
  }
  if (g == 0) {  // 4 lanes per node x 8 ch = all 32 channels
    float dv = dinv[n];
    uint4 xs = ((const uint4*)(xht + (size_t)n * 16))[cq];  // fp16 self-loop
    const __half2* hs = (const __half2*)&xs;
    float2 s0 = __half22float2(hs[0]);
    float2 s1 = __half22float2(hs[1]);
    float2 s2 = __half22float2(hs[2]);
    float2 s3 = __half22float2(hs[3]);
    __half2 o[4];
    o[0] = __floats2half2_rn(dv * (v0 + dv * s0.x), dv * (v1 + dv * s0.y));
    o[1] = __floats2half2_rn(dv * (v2 + dv * s1.x), dv * (v3 + dv * s1.y));
    o[2] = __floats2half2_rn(dv * (v4 + dv * s2.x), dv * (v5 + dv * s2.y));
    o[3] = __floats2half2_rn(dv * (v6 + dv * s3.x), dv * (v7 + dv * s3.y));
    __half2* yp = yG + ((size_t)tl * NN + n) * 16 + cq * 4;
    *(uint4*)yp = *(const uint4*)o;  // 16B store; 4 lanes fill the 64B row
  }
}

// Pass B2: MFMA gate (proven R17/R25/R26/R28/R29). P[64x64] = Y[64x32] @
// M[32x64] per (64-node tile, t) via 16x16x32_f16; B-frags prepacked.
__global__ __launch_bounds__(256) void gate_acc_kernel(
    const __half2* __restrict__ yG, const _Float16* __restrict__ B16,
    const float* __restrict__ Bz, const float* __restrict__ Bh,
    float* __restrict__ acc, int c) {
  int t = threadIdx.x;
  int w = t >> 6;
  int lane = t & 63;
  int nb = blockIdx.x * BSZ;
  int t0 = blockIdx.y * GT;
  int te = min(t0 + GT, c);

  half8_t bf[8];
#pragma unroll
  for (int q = 0; q < 8; ++q)
    bf[q] = *(const half8_t*)(B16 + ((size_t)q * 64 + lane) * 8);
  float bzv[4], bhv[4];
#pragma unroll
  for (int cc = 0; cc < 4; ++cc) {
    bzv[cc] = Bz[cc * 16 + (lane & 15)];
    bhv[cc] = Bh[cc * 16 + (lane & 15)];
  }
  float accr[16];
#pragma unroll
  for (int k = 0; k < 16; ++k) accr[k] = 0.f;

  const _Float16* yF = (const _Float16*)yG;
  int arow = nb + w * 16 + (lane & 15);   // A row this lane loads
  if (arow >= NN) arow = NN - 1;          // tail clamp (results discarded)
  int koff = (lane >> 4) * 8;             // k-offset within the row

  for (int tl = t0; tl < te; ++tl) {
    half8_t a = *(const half8_t*)(yF + ((size_t)tl * NN + arow) * 32 + koff);
    f32x4_t dz0 = {0.f, 0.f, 0.f, 0.f};
    f32x4_t dz[4], dh[4];
#pragma unroll
    for (int cc = 0; cc < 4; ++cc) {
      dz[cc] = __builtin_amdgcn_mfma_f32_16x16x32_f16(a, bf[cc], dz0, 0, 0, 0);
      dh[cc] = __builtin_amdgcn_mfma_f32_16x16x32_f16(a, bf[4 + cc], dz0, 0, 0, 0);
    }
#pragma unroll
    for (int cc = 0; cc < 4; ++cc) {
#pragma unroll
      for (int r = 0; r < 4; ++r) {
        float za = dz[cc][r] + bzv[cc];
        float ha = dh[cc][r] + bhv[cc];
        float z = 1.0f / (1.0f + __expf(-za));
        float th = 1.0f - 2.0f / (__expf(2.f * ha) + 1.0f);
        accr[cc * 4 + r] += (1.0f - z) * th;
      }
    }
  }
#pragma unroll
  for (int cc = 0; cc < 4; ++cc) {
#pragma unroll
    for (int r = 0; r < 4; ++r) {
      int n = nb + w * 16 + (lane >> 4) * 4 + r;
      int j = cc * 16 + (lane & 15);
      if (n < NN) atomicAdd(&acc[(size_t)n * HID + j], accr[cc * 4 + r]);
    }
  }
}

// out[n][o] = (acc[n]/T) . W_out[:,o] + b_out[o]
__global__ __launch_bounds__(256) void out_kernel(const float* __restrict__ acc,
                                                  const float* __restrict__ W_out,
                                                  const float* __restrict__ b_out,
                                                  float* __restrict__ out) {
  __shared__ float sW[HID * OUT_C], sB[OUT_C];
  for (int i = threadIdx.x; i < HID * OUT_C; i += 256) sW[i] = W_out[i];
  if (threadIdx.x < OUT_C) sB[threadIdx.x] = b_out[threadIdx.x];
  __syncthreads();
  unsigned tid = blockIdx.x * 256u + threadIdx.x;
  unsigned n = tid >> 5;
  int o = tid & 31;
  if (n >= NN) return;
  const float* ar = acc + (size_t)n * HID;
  float v = 0.f;
#pragma unroll
  for (int k = 0; k < HID; ++k) v += ar[k] * sW[k * OUT_C + o];
  out[(size_t)n * OUT_C + o] = v * (1.0f / (float)TT) + sB[o];
}

static inline char* alignp(char* p, size_t a) {
  return (char*)(((size_t)p + a - 1) & ~(a - 1));
}

extern "C" void kernel_launch(void* const* d_in, const int* in_sizes, int n_in,
                              void* d_out, int out_size, void* d_ws, size_t ws_size,
                              hipStream_t stream) {
  const float* x     = (const float*)d_in[0];  // [T,N,32]
  const int*   ei    = (const int*)d_in[1];    // [T,2,E]
  const float* ew    = (const float*)d_in[2];  // [T,E]
  const float* Wz    = (const float*)d_in[3];
  const float* bz    = (const float*)d_in[4];
  // d_in[5..6] (Wr,br) dead: H==0 so R unused
  const float* Wh    = (const float*)d_in[7];
  const float* bh    = (const float*)d_in[8];
  const float* Lz_w  = (const float*)d_in[9];
  const float* Lz_b  = (const float*)d_in[10];
  // d_in[11..12] (Lr) dead
  const float* Lh_w  = (const float*)d_in[13];
  const float* Lh_b  = (const float*)d_in[14];
  const float* W_out = (const float*)d_in[15];
  const float* b_out = (const float*)d_in[16];
  float* out = (float*)d_out;

  // per-t sizes (bytes)
  const size_t noffB  = (size_t)(NN + 1) * 4;
  const size_t dinvB  = (size_t)NN * 4;
  const size_t loffB  = (size_t)NN * 4;
  const size_t bbB    = (size_t)NB * 4;
  const size_t rofB   = (size_t)ABLK * (NB + 1) * 4;      // 307 KB
  const size_t sbufB  = (size_t)EE * 4;                   // 3.2 MB
  const size_t bin2B  = (size_t)ABLK * EPB * 8;           // 6.42 MB (y aliases)
  const size_t perT   = noffB + dinvB + loffB + bbB + rofB + sbufB + bin2B;
  const size_t xhB    = XPAIRS * 4;                       // 38.4 MB
  const size_t fixedB = 4 * ((size_t)2 * IN_C * HID + 2 * HID)
                      + 8192 + (size_t)NN * HID * 4 + xhB + 4096;  // ~51.3 MB

  int nt = 12;
  if (ws_size < fixedB + 12 * perT) {
    nt = (int)((ws_size - fixedB) / perT);
    if (nt < 1) nt = 1;
    if (nt > 12) nt = 12;
  }

  char* p = (char*)d_ws;
  unsigned long long* bin2 = (unsigned long long*)p;  // 8-aligned at base
  p += bin2B * nt;
  int* noffG  = (int*)p;          p += noffB * nt;
  float* dinv = (float*)p;        p += dinvB * nt;
  int* loffG  = (int*)p;          p += loffB * nt;
  int* bbase  = (int*)p;          p += bbB * nt;
  int* runoff = (int*)p;          p += rofB * nt;
  unsigned* sbufG = (unsigned*)p; p += sbufB * nt;
  p = alignp(p, 16);
  _Float16* B16 = (_Float16*)p;   p += 8192;  // 4096 fp16 MFMA B-frags
  float* Mz = (float*)p;
  float* Mh = Mz + IN_C * HID;
  float* Bz = Mh + IN_C * HID;
  float* Bh = Bz + HID;
  float* acc = Bh + HID;  // [N,64]
  p = alignp((char*)(acc + (size_t)NN * HID), 256);
  __half2* xh = (__half2*)p;
  // y [nt,N,32] fp16 aliases the bin2 region: bin2 is dead after deg+sort;
  // stream order guarantees sort (reads bin2) < gather_y (writes y) <
  // gate_acc (reads y) < next chunk's bsort (rewrites bin2).
  __half2* yG = (__half2*)bin2;

  prep_kernel<<<dim3(IN_C + 1, 2), 64, 0, stream>>>(Wz, bz, Lz_w, Lz_b, Wh, bh,
                                                    Lh_w, Lh_b, Mz, Bz, Mh, Bh);
  prep_b16_kernel<<<dim3(4, 2), 64, 0, stream>>>(Mz, Mh, B16);
  xconv_kernel<<<(unsigned)((XPAIRS + 255) / 256), 256, 0, stream>>>(x, xh);
  hipMemsetAsync(acc, 0, (size_t)NN * HID * sizeof(float), stream);

  for (int tb = 0; tb < TT; tb += nt) {
    int c = (TT - tb < nt) ? (TT - tb) : nt;
    bsort_kernel<<<dim3(ABLK, c), BST, 0, stream>>>(ei, ew, bin2, runoff, tb);
    deg_kernel<<<dim3(NB, c), 256, 0, stream>>>(runoff, bin2, dinv, loffG);
    bscan_kernel<<<c, 1024, 0, stream>>>(runoff, bbase);
    sort_kernel<<<dim3(NB, c), 256, 0, stream>>>(runoff, bin2, dinv, bbase,
                                                 loffG, sbufG, noffG);
    gather_y_kernel<<<dim3(NN / 8, c), 256, 0, stream>>>(xh, dinv, noffG,
                                                         sbufG, yG, tb);
    gate_acc_kernel<<<dim3(NB, (c + GT - 1) / GT), 256, 0, stream>>>(
        yG, B16, Bz, Bh, acc, c);
  }

  out_kernel<<<(NN * OUT_C + 255) / 256, 256, 0, stream>>>(acc, W_out, b_out, out);
}

// Round 31
// 491.215 us; speedup vs baseline: 1.7234x; 1.0859x over previous
//
#include <hip/hip_runtime.h>
#include <hip/hip_fp16.h>

#define NN 50000
#define TT 12
#define EE 800000
#define IN_C 32
#define HID 64
#define OUT_C 32
#define BSZ 64                        // nodes per bucket
#define NB ((NN + BSZ - 1) / BSZ)     // 782 buckets
#define EPB 8192                      // edges per bsort block (ent fits LDS)
#define ABLK ((EE + EPB - 1) / EPB)   // 98
#define BST 512                       // bsort threads (8 waves: occupancy)
#define GT 4                          // timesteps per gate block
#define XPAIRS ((size_t)TT * NN * 16) // half2 elements in x

typedef _Float16 half8_t __attribute__((ext_vector_type(8)));
typedef float f32x4_t __attribute__((ext_vector_type(4)));

// ---------------- precompute folded gate matrices ----------------
// Mz = Wz @ Lz_w[:64] (32x64), Bz = bz @ Lz_w[:64] + Lz_b (64); same for h.
__global__ __launch_bounds__(64) void prep_kernel(
    const float* __restrict__ Wz, const float* __restrict__ bz,
    const float* __restrict__ Lzw, const float* __restrict__ Lzb,
    const float* __restrict__ Wh, const float* __restrict__ bh,
    const float* __restrict__ Lhw, const float* __restrict__ Lhb,
    float* __restrict__ Mz, float* __restrict__ Bz,
    float* __restrict__ Mh, float* __restrict__ Bh) {
  const int j = threadIdx.x;
  const int i = blockIdx.x;
  const int h = blockIdx.y;
  const float* W  = h ? Wh  : Wz;
  const float* b  = h ? bh  : bz;
  const float* L  = h ? Lhw : Lzw;
  const float* Lb = h ? Lhb : Lzb;
  float* M = h ? Mh : Mz;
  float* B = h ? Bh : Bz;
  if (i < IN_C) {
    float v = 0.f;
    for (int k = 0; k < HID; ++k) v += W[i * HID + k] * L[k * HID + j];
    M[i * HID + j] = v;
  } else {
    float v = Lb[j];
    for (int k = 0; k < HID; ++k) v += b[k] * L[k * HID + j];
    B[j] = v;
  }
}

// pack M into MFMA B-operand fp16 layout: B16[(g*4+cc)*64 + lane][i] =
// M_g[k = 8*(lane>>4)+i][col = cc*16 + (lane&15)]
__global__ __launch_bounds__(64) void prep_b16_kernel(
    const float* __restrict__ Mz, const float* __restrict__ Mh,
    _Float16* __restrict__ B16) {
  int l = threadIdx.x;
  int cc = blockIdx.x;  // coltile 0..3
  int g = blockIdx.y;   // 0=z, 1=h
  const float* M = g ? Mh : Mz;
#pragma unroll
  for (int i = 0; i < 8; ++i) {
    int k = (l >> 4) * 8 + i;
    int col = cc * 16 + (l & 15);
    B16[(((size_t)g * 4 + cc) * 64 + l) * 8 + i] = (_Float16)M[k * HID + col];
  }
}

// x [T,N,32] fp32 -> fp16 pairs
__global__ __launch_bounds__(256) void xconv_kernel(const float* __restrict__ x,
                                                    __half2* __restrict__ xh) {
  size_t i = (size_t)blockIdx.x * 256 + threadIdx.x;
  if (i < XPAIRS) {
    float2 f = ((const float2*)x)[i];
    xh[i] = __floats2half2_rn(f.x, f.y);
  }
}

// bsort v4 (VALIDATED R30): LDS-staged sort + sequential streamout at
// 512 threads. Coalesced reads, sequential writes: amp ~1.0 both sides.
__global__ __launch_bounds__(BST) void bsort_kernel(
    const int* __restrict__ ei, const float* __restrict__ ew,
    unsigned long long* __restrict__ bin2G, int* __restrict__ runoffG,
    int tbase) {
  __shared__ int hist[NB];
  __shared__ int rnk[NB];
  __shared__ int lbase[NB + 1];
  __shared__ unsigned long long sent[EPB];  // 64 KB sorted-entry buffer
  int tl = blockIdx.y;
  const int* src = ei + (size_t)(tbase + tl) * 2 * EE;
  const int* dst = src + EE;
  const float* w = ew + (size_t)(tbase + tl) * EE;
  int t = threadIdx.x;
  for (int i = t; i < NB; i += BST) { hist[i] = 0; rnk[i] = 0; }
  __syncthreads();
  int e0 = blockIdx.x * EPB;
  int cnt = min(EPB, EE - e0);
  for (int i = t; i < cnt; i += BST) atomicAdd(&hist[dst[e0 + i] >> 6], 1);
  __syncthreads();
  if (t == 0) {
    int run = 0;
    for (int b = 0; b < NB; ++b) { lbase[b] = run; run += hist[b]; }
    lbase[NB] = run;  // == cnt
  }
  __syncthreads();
  int* rof = runoffG + ((size_t)tl * ABLK + blockIdx.x) * (NB + 1);
  for (int b = t; b < NB + 1; b += BST) rof[b] = lbase[b];
  for (int i = t; i < cnt; i += BST) {
    int d = dst[e0 + i], s = src[e0 + i];
    int b = d >> 6;
    unsigned short hw = __half_as_ushort(__float2half_rn(w[e0 + i]));
    int pos = lbase[b] + atomicAdd(&rnk[b], 1);
    sent[pos] = (unsigned long long)((unsigned)s | ((unsigned)(d & 63) << 16)) |
                ((unsigned long long)hw << 32);
  }
  __syncthreads();
  unsigned long long* reg = bin2G + ((size_t)tl * ABLK + blockIdx.x) * EPB;
  for (int i = t; i < cnt; i += BST) reg[i] = sent[i];
}

// bscan v2 (VALIDATED R26): bucket totals from runoff diffs + 1024-wide scan.
__global__ __launch_bounds__(1024) void bscan_kernel(const int* __restrict__ runoffG,
                                                     int* __restrict__ bbaseA) {
  __shared__ int s[1024];
  int tl = blockIdx.x, t = threadIdx.x;
  const int* runoff = runoffG + (size_t)tl * ABLK * (NB + 1);
  int v = 0;
  if (t < NB) {
    for (int blk = 0; blk < ABLK; ++blk)
      v += runoff[blk * (NB + 1) + t + 1] - runoff[blk * (NB + 1) + t];
  }
  s[t] = v;
  __syncthreads();
  for (int o = 1; o < 1024; o <<= 1) {
    int u = (t >= o) ? s[t - o] : 0;
    __syncthreads();
    s[t] += u;
    __syncthreads();
  }
  if (t < NB) bbaseA[(size_t)tl * NB + t] = s[t] - v;  // exclusive
}

// sortdeg: deg v3 (VALIDATED R29) and sort v4 (VALIDATED R29) MERGED.
// R30's split cost two separate HBM streams of bin2 (77 MB each) because
// the kernel boundary evicted L2. Here pass 1 (wsum+cnt LDS atomics) and
// pass 2 (place) run in ONE block: the place pass re-reads the block's own
// ~8 KB of runs L1/L2-hot. To break the cross-bucket dinv[src] dependency
// that forced the split, sbuf now stores RAW fp16 w; gather multiplies by
// dinv[src] (L2-resident 200 KB table).
__global__ __launch_bounds__(256) void sortdeg_kernel(
    const int* __restrict__ runoffG, const unsigned long long* __restrict__ bin2G,
    const int* __restrict__ bbaseA, float* __restrict__ dinvA,
    unsigned* __restrict__ sbufG, int* __restrict__ noffG) {
  __shared__ float wsum[BSZ];
  __shared__ int cnt[BSZ];
  __shared__ int plc[BSZ];
  __shared__ int loff[BSZ];
  int tl = blockIdx.y, b = blockIdx.x;
  int t = threadIdx.x;
  if (t < BSZ) { wsum[t] = 0.f; cnt[t] = 0; }
  __syncthreads();
  const int* runoff = runoffG + (size_t)tl * ABLK * (NB + 1);
  int g = t >> 5;      // lane-group 0..7
  int lane = t & 31;
  // pass 1: wsum + cnt over the bucket's runs
  for (int blk = g; blk < ABLK; blk += 8) {
    int r0 = runoff[blk * (NB + 1) + b];
    int r1 = runoff[blk * (NB + 1) + b + 1];
    const unsigned long long* reg = bin2G + ((size_t)tl * ABLK + blk) * EPB;
    for (int i = r0 + lane; i < r1; i += 32) {
      unsigned long long u = reg[i];
      int dl = (int)((u >> 16) & 63u);
      atomicAdd(&wsum[dl], __half2float(__ushort_as_half((unsigned short)(u >> 32))));
      atomicAdd(&cnt[dl], 1);
    }
  }
  __syncthreads();
  if (t == 0) {
    int run = 0;
#pragma unroll
    for (int i = 0; i < BSZ; ++i) { loff[i] = run; run += cnt[i]; }
  }
  __syncthreads();
  int base = bbaseA[(size_t)tl * NB + b];
  int* noff = noffG + (size_t)tl * (NN + 1);
  if (t < BSZ) {
    int n = b * BSZ + t;
    int v = base + loff[t];
    plc[t] = v;
    if (n < NN) {
      noff[n] = v;
      dinvA[(size_t)tl * NN + n] = rsqrtf(1.0f + wsum[t]);
    }
  }
  if (b == 0 && t == 0) noff[NN] = EE;
  __syncthreads();
  unsigned* sbuf = sbufG + (size_t)tl * EE;
  // pass 2: place {src16 | raw fp16 w << 16} (runs L1/L2-hot from pass 1)
  for (int blk = g; blk < ABLK; blk += 8) {
    int r0 = runoff[blk * (NB + 1) + b];
    int r1 = runoff[blk * (NB + 1) + b + 1];
    const unsigned long long* reg = bin2G + ((size_t)tl * ABLK + blk) * EPB;
    for (int i = r0 + lane; i < r1; i += 32) {
      unsigned long long u = reg[i];
      int pos = atomicAdd(&plc[(int)((u >> 16) & 63u)], 1);
      sbuf[pos] = (unsigned)(u & 0xFFFFu) | ((unsigned)(u >> 32) << 16);
    }
  }
}

// Pass B1: pure gather (VALIDATED R30 structure); nm = w * dinv[src] now
// computed here (dinv 200 KB/t, L2-resident, 4-lane broadcast).
__global__ __launch_bounds__(256) void gather_y_kernel(
    const __half2* __restrict__ xh,
    const float* __restrict__ dinvA, const int* __restrict__ noffG,
    const unsigned* __restrict__ sbufG, __half2* __restrict__ yG, int tbase) {
  int t = threadIdx.x;
  int w = t >> 6;            // wave 0..3
  int lane = t & 63;
  int h2 = lane >> 5;        // node half 0/1
  int g = (lane >> 2) & 7;   // edge group 0..7
  int cq = lane & 3;         // channel oct 0..3 (8 fp16 ch = uint4)
  int tl = blockIdx.y;
  int n = blockIdx.x * 8 + w * 2 + h2;  // NN % 8 == 0, no tail

  const float* dinv = dinvA + (size_t)tl * NN;
  const int* noff = noffG + (size_t)tl * (NN + 1);
  const unsigned* sbuf = sbufG + (size_t)tl * EE;
  const __half2* xht = xh + (size_t)(tbase + tl) * NN * 16;

  int e0 = noff[n], e1 = noff[n + 1];
  float v0 = 0.f, v1 = 0.f, v2 = 0.f, v3 = 0.f;
  float v4 = 0.f, v5 = 0.f, v6 = 0.f, v7 = 0.f;
  for (int e = e0 + g; e < e1; e += 8) {
    unsigned u = sbuf[e];  // 4 lanes same addr: broadcast
    int s = (int)(u & 0xFFFFu);
    float nm = __half2float(__ushort_as_half((unsigned short)(u >> 16))) * dinv[s];
    uint4 xr = ((const uint4*)(xht + (size_t)s * 16))[cq];
    const __half2* hp = (const __half2*)&xr;
    float2 f0 = __half22float2(hp[0]);
    float2 f1 = __half22float2(hp[1]);
    float2 f2 = __half22float2(hp[2]);
    float2 f3 = __half22float2(hp[3]);
    v0 += nm * f0.x; v1 += nm * f0.y;
    v2 += nm * f1.x; v3 += nm * f1.y;
    v4 += nm * f2.x; v5 += nm * f2.y;
    v6 += nm * f3.x; v7 += nm * f3.y;
  }
  // reduce over the 8 edge groups (lane bits 2,3,4 — stays in node half/oct)
#pragma unroll
  for (int m = 4; m <= 16; m <<= 1) {
    v0 += __shfl_xor(v0, m); v1 += __shfl_xor(v1, m);
    v2 += __shfl_xor(v2, m); v3 += __shfl_xor(v3, m);
    v4 += __shfl_xor(v4, m); v5 += __shfl_xor(v5, m);
    v6 += __shfl_xor(v6, m); v7 += __shfl_xor(v7, m);
  }
  if (g == 0) {  // 4 lanes per node x 8 ch = all 32 channels
    float dv = dinv[n];
    uint4 xs = ((const uint4*)(xht + (size_t)n * 16))[cq];  // fp16 self-loop
    const __half2* hs = (const __half2*)&xs;
    float2 s0 = __half22float2(hs[0]);
    float2 s1 = __half22float2(hs[1]);
    float2 s2 = __half22float2(hs[2]);
    float2 s3 = __half22float2(hs[3]);
    __half2 o[4];
    o[0] = __floats2half2_rn(dv * (v0 + dv * s0.x), dv * (v1 + dv * s0.y));
    o[1] = __floats2half2_rn(dv * (v2 + dv * s1.x), dv * (v3 + dv * s1.y));
    o[2] = __floats2half2_rn(dv * (v4 + dv * s2.x), dv * (v5 + dv * s2.y));
    o[3] = __floats2half2_rn(dv * (v6 + dv * s3.x), dv * (v7 + dv * s3.y));
    __half2* yp = yG + ((size_t)tl * NN + n) * 16 + cq * 4;
    *(uint4*)yp = *(const uint4*)o;  // 16B store; 4 lanes fill the 64B row
  }
}

// Pass B2: MFMA gate (proven R17/R25/R26/R28/R29/R30). P[64x64] = Y[64x32]
// @ M[32x64] per (64-node tile, t) via 16x16x32_f16; B-frags prepacked.
__global__ __launch_bounds__(256) void gate_acc_kernel(
    const __half2* __restrict__ yG, const _Float16* __restrict__ B16,
    const float* __restrict__ Bz, const float* __restrict__ Bh,
    float* __restrict__ acc, int c) {
  int t = threadIdx.x;
  int w = t >> 6;
  int lane = t & 63;
  int nb = blockIdx.x * BSZ;
  int t0 = blockIdx.y * GT;
  int te = min(t0 + GT, c);

  half8_t bf[8];
#pragma unroll
  for (int q = 0; q < 8; ++q)
    bf[q] = *(const half8_t*)(B16 + ((size_t)q * 64 + lane) * 8);
  float bzv[4], bhv[4];
#pragma unroll
  for (int cc = 0; cc < 4; ++cc) {
    bzv[cc] = Bz[cc * 16 + (lane & 15)];
    bhv[cc] = Bh[cc * 16 + (lane & 15)];
  }
  float accr[16];
#pragma unroll
  for (int k = 0; k < 16; ++k) accr[k] = 0.f;

  const _Float16* yF = (const _Float16*)yG;
  int arow = nb + w * 16 + (lane & 15);   // A row this lane loads
  if (arow >= NN) arow = NN - 1;          // tail clamp (results discarded)
  int koff = (lane >> 4) * 8;             // k-offset within the row

  for (int tl = t0; tl < te; ++tl) {
    half8_t a = *(const half8_t*)(yF + ((size_t)tl * NN + arow) * 32 + koff);
    f32x4_t dz0 = {0.f, 0.f, 0.f, 0.f};
    f32x4_t dz[4], dh[4];
#pragma unroll
    for (int cc = 0; cc < 4; ++cc) {
      dz[cc] = __builtin_amdgcn_mfma_f32_16x16x32_f16(a, bf[cc], dz0, 0, 0, 0);
      dh[cc] = __builtin_amdgcn_mfma_f32_16x16x32_f16(a, bf[4 + cc], dz0, 0, 0, 0);
    }
#pragma unroll
    for (int cc = 0; cc < 4; ++cc) {
#pragma unroll
      for (int r = 0; r < 4; ++r) {
        float za = dz[cc][r] + bzv[cc];
        float ha = dh[cc][r] + bhv[cc];
        float z = 1.0f / (1.0f + __expf(-za));
        float th = 1.0f - 2.0f / (__expf(2.f * ha) + 1.0f);
        accr[cc * 4 + r] += (1.0f - z) * th;
      }
    }
  }
#pragma unroll
  for (int cc = 0; cc < 4; ++cc) {
#pragma unroll
    for (int r = 0; r < 4; ++r) {
      int n = nb + w * 16 + (lane >> 4) * 4 + r;
      int j = cc * 16 + (lane & 15);
      if (n < NN) atomicAdd(&acc[(size_t)n * HID + j], accr[cc * 4 + r]);
    }
  }
}

// out[n][o] = (acc[n]/T) . W_out[:,o] + b_out[o]
__global__ __launch_bounds__(256) void out_kernel(const float* __restrict__ acc,
                                                  const float* __restrict__ W_out,
                                                  const float* __restrict__ b_out,
                                                  float* __restrict__ out) {
  __shared__ float sW[HID * OUT_C], sB[OUT_C];
  for (int i = threadIdx.x; i < HID * OUT_C; i += 256) sW[i] = W_out[i];
  if (threadIdx.x < OUT_C) sB[threadIdx.x] = b_out[threadIdx.x];
  __syncthreads();
  unsigned tid = blockIdx.x * 256u + threadIdx.x;
  unsigned n = tid >> 5;
  int o = tid & 31;
  if (n >= NN) return;
  const float* ar = acc + (size_t)n * HID;
  float v = 0.f;
#pragma unroll
  for (int k = 0; k < HID; ++k) v += ar[k] * sW[k * OUT_C + o];
  out[(size_t)n * OUT_C + o] = v * (1.0f / (float)TT) + sB[o];
}

static inline char* alignp(char* p, size_t a) {
  return (char*)(((size_t)p + a - 1) & ~(a - 1));
}

extern "C" void kernel_launch(void* const* d_in, const int* in_sizes, int n_in,
                              void* d_out, int out_size, void* d_ws, size_t ws_size,
                              hipStream_t stream) {
  const float* x     = (const float*)d_in[0];  // [T,N,32]
  const int*   ei    = (const int*)d_in[1];    // [T,2,E]
  const float* ew    = (const float*)d_in[2];  // [T,E]
  const float* Wz    = (const float*)d_in[3];
  const float* bz    = (const float*)d_in[4];
  // d_in[5..6] (Wr,br) dead: H==0 so R unused
  const float* Wh    = (const float*)d_in[7];
  const float* bh    = (const float*)d_in[8];
  const float* Lz_w  = (const float*)d_in[9];
  const float* Lz_b  = (const float*)d_in[10];
  // d_in[11..12] (Lr) dead
  const float* Lh_w  = (const float*)d_in[13];
  const float* Lh_b  = (const float*)d_in[14];
  const float* W_out = (const float*)d_in[15];
  const float* b_out = (const float*)d_in[16];
  float* out = (float*)d_out;

  // per-t sizes (bytes)
  const size_t noffB  = (size_t)(NN + 1) * 4;
  const size_t dinvB  = (size_t)NN * 4;
  const size_t bbB    = (size_t)NB * 4;
  const size_t rofB   = (size_t)ABLK * (NB + 1) * 4;      // 307 KB
  const size_t sbufB  = (size_t)EE * 4;                   // 3.2 MB
  const size_t bin2B  = (size_t)ABLK * EPB * 8;           // 6.42 MB (y aliases)
  const size_t perT   = noffB + dinvB + bbB + rofB + sbufB + bin2B;
  const size_t xhB    = XPAIRS * 4;                       // 38.4 MB
  const size_t fixedB = 4 * ((size_t)2 * IN_C * HID + 2 * HID)
                      + 8192 + (size_t)NN * HID * 4 + xhB + 4096;  // ~51.3 MB

  int nt = 12;
  if (ws_size < fixedB + 12 * perT) {
    nt = (int)((ws_size - fixedB) / perT);
    if (nt < 1) nt = 1;
    if (nt > 12) nt = 12;
  }

  char* p = (char*)d_ws;
  unsigned long long* bin2 = (unsigned long long*)p;  // 8-aligned at base
  p += bin2B * nt;
  int* noffG  = (int*)p;          p += noffB * nt;
  float* dinv = (float*)p;        p += dinvB * nt;
  int* bbase  = (int*)p;          p += bbB * nt;
  int* runoff = (int*)p;          p += rofB * nt;
  unsigned* sbufG = (unsigned*)p; p += sbufB * nt;
  p = alignp(p, 16);
  _Float16* B16 = (_Float16*)p;   p += 8192;  // 4096 fp16 MFMA B-frags
  float* Mz = (float*)p;
  float* Mh = Mz + IN_C * HID;
  float* Bz = Mh + IN_C * HID;
  float* Bh = Bz + HID;
  float* acc = Bh + HID;  // [N,64]
  p = alignp((char*)(acc + (size_t)NN * HID), 256);
  __half2* xh = (__half2*)p;
  // y [nt,N,32] fp16 aliases the bin2 region: bin2 is dead after sortdeg;
  // stream order guarantees sortdeg (reads bin2) < gather_y (writes y) <
  // gate_acc (reads y) < next chunk's bsort (rewrites bin2).
  __half2* yG = (__half2*)bin2;

  prep_kernel<<<dim3(IN_C + 1, 2), 64, 0, stream>>>(Wz, bz, Lz_w, Lz_b, Wh, bh,
                                                    Lh_w, Lh_b, Mz, Bz, Mh, Bh);
  prep_b16_kernel<<<dim3(4, 2), 64, 0, stream>>>(Mz, Mh, B16);
  xconv_kernel<<<(unsigned)((XPAIRS + 255) / 256), 256, 0, stream>>>(x, xh);
  hipMemsetAsync(acc, 0, (size_t)NN * HID * sizeof(float), stream);

  for (int tb = 0; tb < TT; tb += nt) {
    int c = (TT - tb < nt) ? (TT - tb) : nt;
    bsort_kernel<<<dim3(ABLK, c), BST, 0, stream>>>(ei, ew, bin2, runoff, tb);
    bscan_kernel<<<c, 1024, 0, stream>>>(runoff, bbase);
    sortdeg_kernel<<<dim3(NB, c), 256, 0, stream>>>(runoff, bin2, bbase,
                                                    dinv, sbufG, noffG);
    gather_y_kernel<<<dim3(NN / 8, c), 256, 0, stream>>>(xh, dinv, noffG,
                                                         sbufG, yG, tb);
    gate_acc_kernel<<<dim3(NB, (c + GT - 1) / GT), 256, 0, stream>>>(
        yG, B16, Bz, Bh, acc, c);
  }

  out_kernel<<<(NN * OUT_C + 255) / 256, 256, 0, stream>>>(acc, W_out, b_out, out);
}